// Round 3
// baseline (769.950 us; speedup 1.0000x reference)
//
#include <hip/hip_runtime.h>
#include <hip/hip_bf16.h>

typedef __hip_bfloat16 bf16;
typedef __attribute__((ext_vector_type(8))) short bf16x8;
typedef __attribute__((ext_vector_type(4))) float f32x4;

#define SEQ     2048
#define DMODEL  1024
#define DINNER  2048
#define NBATCH  4
#define NROWS   (NBATCH * SEQ)   // 8192
#define DSTATE  16
#define NCHUNK  16
#define CHUNK   128              // SEQ / NCHUNK

__device__ __forceinline__ float b2f(short s) {
    union { unsigned u; float f; } c;
    c.u = ((unsigned)(unsigned short)s) << 16;
    return c.f;
}

// async global->LDS, 16B per lane; LDS dest = l + lane*16 (wave-uniform base)
__device__ __forceinline__ void async16(const bf16* g, bf16* l) {
    __builtin_amdgcn_global_load_lds(
        (const __attribute__((address_space(1))) void*)g,
        (__attribute__((address_space(3))) void*)l, 16, 0, 0);
}

// ---------------------------------------------------------------------------
// Transpose + cast fp32 (K x N) -> bf16 (Npad x K), zero-filling rows >= N.
// ---------------------------------------------------------------------------
__global__ __launch_bounds__(256)
void transpose_cast(const float* __restrict__ W, bf16* __restrict__ WT,
                    int K, int N, int Npad)
{
    __shared__ float tile[32][33];
    const int bx = blockIdx.x;            // along N (padded)
    const int by = blockIdx.y;            // along K
    const int tx = threadIdx.x, ty = threadIdx.y;
    const int x = bx * 32 + tx;           // N index
#pragma unroll
    for (int i = 0; i < 32; i += 8) {
        int y = by * 32 + ty + i;         // K index
        tile[ty + i][tx] = (x < N && y < K) ? W[(size_t)y * N + x] : 0.f;
    }
    __syncthreads();
    const int k = by * 32 + tx;
#pragma unroll
    for (int i = 0; i < 32; i += 8) {
        int n = bx * 32 + ty + i;
        if (n < Npad && k < K)
            WT[(size_t)n * K + k] = __float2bfloat16(tile[tx][ty + i]);
    }
}

// ---------------------------------------------------------------------------
// Elementwise fp32 -> bf16 cast
// ---------------------------------------------------------------------------
__global__ __launch_bounds__(256)
void cast_to_bf16(const float* __restrict__ in, bf16* __restrict__ out, int n4)
{
    int i = blockIdx.x * 256 + threadIdx.x;
    if (i < n4) {
        float4 v = *(const float4*)(in + (size_t)i * 4);
        __align__(8) bf16 o[4] = { __float2bfloat16(v.x), __float2bfloat16(v.y),
                                   __float2bfloat16(v.z), __float2bfloat16(v.w) };
        *(uint2*)(out + (size_t)i * 4) = *(uint2*)o;
    }
}

// ---------------------------------------------------------------------------
// GEMM: C[M,N] = A[M,K] @ B^T[N,K]   (bf16 in, fp32 accum).
// A row stride lda, BT row stride ldb (compact = K), C row stride ldc.
// MODE 0: store fp32.  MODE 2: store bf16.
// MODE 3: merged dt/bdt epilogue — col <  DINNER: bf16 softplus(acc+bias[col])
//                                  col >= DINNER: fp32 to Cf[(row)*128+col-DINNER]
// 128x128 tile, BK=32, 256 threads (4 waves, 64x64 each, 4x4 MFMA tiles).
// Staging via global_load_lds width=16 (m97 structure): per wave 2 instrs per
// matrix, each covering 16 rows (64 B/row) of the row-major 128x32 LDS tile.
// ---------------------------------------------------------------------------
template <int MODE>
__global__ __launch_bounds__(256, 2)
void gemm_bt(const bf16* __restrict__ A, int lda, const bf16* __restrict__ BT,
             int ldb, float* __restrict__ Cf, bf16* __restrict__ Cb, int ldc,
             const float* __restrict__ bias, int K)
{
    __shared__ __align__(16) bf16 As[128 * 32];
    __shared__ __align__(16) bf16 Bs[128 * 32];
    const int tid  = threadIdx.x;
    const int lane = tid & 63;
    const int wave = tid >> 6;
    const int m0 = blockIdx.y * 128;
    const int n0 = blockIdx.x * 128;
    const int wm = (wave & 1) * 64;
    const int wn = (wave >> 1) * 64;

    f32x4 acc[4][4];
#pragma unroll
    for (int i = 0; i < 4; ++i)
#pragma unroll
        for (int j = 0; j < 4; ++j) acc[i][j] = (f32x4){0.f, 0.f, 0.f, 0.f};

    // per-lane global sources for the 2 staging instructions per matrix:
    // instr (wave,i) covers tile rows [(wave*2+i)*16, +16); lane l -> row l>>2,
    // col chunk (l&3)*8 — matches LDS dest base + l*16 in row-major 128x32.
    const int r16 = lane >> 2;
    const int cc  = (lane & 3) * 8;
    const bf16* gA0 = A  + (size_t)(m0 + wave * 32 +      r16) * lda + cc;
    const bf16* gA1 = A  + (size_t)(m0 + wave * 32 + 16 + r16) * lda + cc;
    const bf16* gB0 = BT + (size_t)(n0 + wave * 32 +      r16) * ldb + cc;
    const bf16* gB1 = BT + (size_t)(n0 + wave * 32 + 16 + r16) * ldb + cc;
    bf16* lA0 = As + (wave * 2 + 0) * 512;   // 512 elem = 1024 B = 16 rows
    bf16* lA1 = As + (wave * 2 + 1) * 512;
    bf16* lB0 = Bs + (wave * 2 + 0) * 512;
    bf16* lB1 = Bs + (wave * 2 + 1) * 512;

    const int arow = lane & 15;
    const int akq  = (lane >> 4) * 8;
    const int KT = K >> 5;

    for (int kt = 0; kt < KT; ++kt) {
        __syncthreads();                 // prior LDS reads done before overwrite
        async16(gA0, lA0);
        async16(gA1, lA1);
        async16(gB0, lB0);
        async16(gB1, lB1);
        gA0 += 32; gA1 += 32; gB0 += 32; gB1 += 32;
        __syncthreads();                 // drains vmcnt -> staging visible
        bf16x8 af[4], bfr[4];
#pragma unroll
        for (int i = 0; i < 4; ++i)
            af[i] = *(const bf16x8*)(As + (wm + i * 16 + arow) * 32 + akq);
#pragma unroll
        for (int j = 0; j < 4; ++j)
            bfr[j] = *(const bf16x8*)(Bs + (wn + j * 16 + arow) * 32 + akq);
#pragma unroll
        for (int i = 0; i < 4; ++i)
#pragma unroll
            for (int j = 0; j < 4; ++j)
                acc[i][j] = __builtin_amdgcn_mfma_f32_16x16x32_bf16(
                    af[i], bfr[j], acc[i][j], 0, 0, 0);
    }

    // epilogue: C/D layout col = lane&15, row = (lane>>4)*4 + reg
    const int rbase = (lane >> 4) * 4;
    const int cbase = lane & 15;
#pragma unroll
    for (int i = 0; i < 4; ++i) {
        int row = m0 + wm + i * 16 + rbase;
#pragma unroll
        for (int j = 0; j < 4; ++j) {
            int col = n0 + wn + j * 16 + cbase;
#pragma unroll
            for (int r = 0; r < 4; ++r) {
                float v = acc[i][j][r];
                if (MODE == 0) {
                    Cf[(size_t)(row + r) * ldc + col] = v;
                } else if (MODE == 2) {
                    Cb[(size_t)(row + r) * ldc + col] = __float2bfloat16(v);
                } else {   // MODE 3 (uniform per block: n0==2048 -> bdt path)
                    if (col < DINNER) {
                        float v2 = v + bias[col];
                        float sp = (v2 > 20.f) ? v2 : log1pf(__expf(v2));
                        Cb[(size_t)(row + r) * ldc + col] = __float2bfloat16(sp);
                    } else {
                        Cf[(size_t)(row + r) * 128 + (col - DINNER)] = v;
                    }
                }
            }
        }
    }
}

// ---------------------------------------------------------------------------
// Causal depthwise conv (d_conv=4) + bias + SiLU. Reads bf16 x_inner =
// xz[:, :2048] (row stride 4096). One thread per (row, 8 channels).
// ---------------------------------------------------------------------------
__global__ __launch_bounds__(256)
void conv_silu(const bf16* __restrict__ xz, const float* __restrict__ conv_w,
               const float* __restrict__ conv_b, bf16* __restrict__ xc)
{
    int gid = blockIdx.x * 256 + threadIdx.x;   // NROWS * 256
    int d8  = gid & 255;
    int row = gid >> 8;
    int l   = row & (SEQ - 1);
    int d   = d8 * 8;
    const bf16* base = xz + (size_t)row * 4096 + d;
    float acc[8];
    float4 b0 = *(const float4*)(conv_b + d);
    float4 b1 = *(const float4*)(conv_b + d + 4);
    acc[0] = b0.x; acc[1] = b0.y; acc[2] = b0.z; acc[3] = b0.w;
    acc[4] = b1.x; acc[5] = b1.y; acc[6] = b1.z; acc[7] = b1.w;
    float w[8][4];
#pragma unroll
    for (int j = 0; j < 8; ++j) {
        float4 wv = *(const float4*)(conv_w + (size_t)(d + j) * 4);
        w[j][0] = wv.x; w[j][1] = wv.y; w[j][2] = wv.z; w[j][3] = wv.w;
    }
#pragma unroll
    for (int k = 0; k < 4; ++k) {
        if (l + k - 3 >= 0) {   // wave-uniform branch (row is block-uniform)
            bf16x8 v = *(const bf16x8*)(base + (ptrdiff_t)(k - 3) * 4096);
#pragma unroll
            for (int j = 0; j < 8; ++j)
                acc[j] = fmaf(b2f(v[j]), w[j][k], acc[j]);
        }
    }
    __align__(16) bf16 o[8];
#pragma unroll
    for (int j = 0; j < 8; ++j) {
        float s = acc[j] / (1.f + __expf(-acc[j]));
        o[j] = __float2bfloat16(s);
    }
    *(bf16x8*)(xc + (size_t)row * DINNER + d) = *(bf16x8*)o;
}

// ---------------------------------------------------------------------------
// Chunked selective scan, pass 1: per (b, chunk, d): P = prod(a_t), S = local h
// layout P/S[c][b][d][n]
// ---------------------------------------------------------------------------
__global__ __launch_bounds__(256)
void scan_pass1(const bf16* __restrict__ xc, const bf16* __restrict__ dt,
                const float* __restrict__ bdt, const float* __restrict__ A_log,
                float* __restrict__ P, float* __restrict__ S)
{
    const int d  = blockIdx.x * 256 + threadIdx.x;
    const int c  = blockIdx.y;
    const int b  = blockIdx.z;
    const int t0 = c * CHUNK;
    __shared__ float bls[CHUNK][DSTATE];
    for (int i = threadIdx.x; i < CHUNK * DSTATE; i += 256) {
        int tl = i >> 4, col = i & 15;
        bls[tl][col] = bdt[(size_t)(b * SEQ + t0 + tl) * 128 + col];
    }
    __syncthreads();
    float acoef[16], h[16], p[16];
#pragma unroll
    for (int n = 0; n < 16; ++n) {
        acoef[n] = -__expf(A_log[(size_t)d * 16 + n]) * 1.44269504f;
        h[n] = 0.f; p[n] = 1.f;
    }
    size_t idx = (size_t)(b * SEQ + t0) * DINNER + d;
    for (int tl = 0; tl < CHUNK; ++tl, idx += DINNER) {
        float dtv = __bfloat162float(dt[idx]);
        float xv  = __bfloat162float(xc[idx]);
        float u = dtv * xv;
#pragma unroll
        for (int n = 0; n < 16; ++n) {
            float a = exp2f(dtv * acoef[n]);
            p[n] *= a;
            h[n] = fmaf(a, h[n], u * bls[tl][n]);
        }
    }
    size_t o = ((size_t)(c * NBATCH + b) * DINNER + d) * 16;
#pragma unroll
    for (int n = 0; n < 16; n += 4) {
        *(float4*)(P + o + n) = make_float4(p[n], p[n+1], p[n+2], p[n+3]);
        *(float4*)(S + o + n) = make_float4(h[n], h[n+1], h[n+2], h[n+3]);
    }
}

// ---------------------------------------------------------------------------
// Pass 2: sequential combine over chunks. One thread per (b,d,n).
// Hinit may alias P (each element read before overwrite, one owner thread).
// ---------------------------------------------------------------------------
__global__ __launch_bounds__(256)
void scan_pass2(const float* __restrict__ P, const float* __restrict__ S,
                float* __restrict__ Hinit)
{
    size_t idx = (size_t)blockIdx.x * 256 + threadIdx.x;
    const size_t stride = (size_t)NBATCH * DINNER * 16;
    float h = 0.f;
    for (int c = 0; c < NCHUNK; ++c) {
        size_t o = (size_t)c * stride + idx;
        float p = P[o];
        float s = S[o];
        Hinit[o] = h;
        h = fmaf(p, h, s);
    }
}

// ---------------------------------------------------------------------------
// Pass 3: replay chunk from true h_init; fuse y = scan + xc*D, * silu(z),
// cast bf16 into U (row stride 4096; reads z from cols 2048.. of same buffer)
// ---------------------------------------------------------------------------
__global__ __launch_bounds__(256)
void scan_pass3(const bf16* __restrict__ xc, const bf16* __restrict__ dt,
                const float* __restrict__ bdt, const float* __restrict__ A_log,
                const float* __restrict__ Hinit, const bf16* __restrict__ xzb,
                const float* __restrict__ Dp, bf16* __restrict__ U)
{
    const int d  = blockIdx.x * 256 + threadIdx.x;
    const int c  = blockIdx.y;
    const int b  = blockIdx.z;
    const int t0 = c * CHUNK;
    __shared__ float bls[CHUNK][DSTATE];
    __shared__ float cls[CHUNK][DSTATE];
    for (int i = threadIdx.x; i < CHUNK * 32; i += 256) {
        int tl = i >> 5, col = i & 31;
        float v = bdt[(size_t)(b * SEQ + t0 + tl) * 128 + col];
        if (col < 16) bls[tl][col] = v; else cls[tl][col - 16] = v;
    }
    __syncthreads();
    float acoef[16], h[16];
#pragma unroll
    for (int n = 0; n < 16; ++n)
        acoef[n] = -__expf(A_log[(size_t)d * 16 + n]) * 1.44269504f;
    size_t ho = ((size_t)(c * NBATCH + b) * DINNER + d) * 16;
#pragma unroll
    for (int n = 0; n < 16; n += 4) {
        float4 hv = *(const float4*)(Hinit + ho + n);
        h[n] = hv.x; h[n+1] = hv.y; h[n+2] = hv.z; h[n+3] = hv.w;
    }
    const float Dv = Dp[d];
    size_t idx  = (size_t)(b * SEQ + t0) * DINNER + d;
    size_t widx = (size_t)(b * SEQ + t0) * 4096 + d;   // U col d / z col 2048+d
    for (int tl = 0; tl < CHUNK; ++tl, idx += DINNER, widx += 4096) {
        float dtv = __bfloat162float(dt[idx]);
        float xv  = __bfloat162float(xc[idx]);
        float u = dtv * xv;
        float y = 0.f;
#pragma unroll
        for (int n = 0; n < 16; ++n) {
            float a = exp2f(dtv * acoef[n]);
            h[n] = fmaf(a, h[n], u * bls[tl][n]);
            y = fmaf(h[n], cls[tl][n], y);
        }
        float zv = __bfloat162float(xzb[widx + DINNER]);
        float sz = zv / (1.f + __expf(-zv));
        float val = (y + xv * Dv) * sz;
        U[widx] = __float2bfloat16(val);
    }
}

// ---------------------------------------------------------------------------
extern "C" void kernel_launch(void* const* d_in, const int* in_sizes, int n_in,
                              void* d_out, int out_size, void* d_ws, size_t ws_size,
                              hipStream_t stream)
{
    const float* x      = (const float*)d_in[0];
    const float* W_in   = (const float*)d_in[1];
    const float* conv_w = (const float*)d_in[2];
    const float* conv_b = (const float*)d_in[3];
    const float* W_x    = (const float*)d_in[4];
    const float* W_dt   = (const float*)d_in[5];
    const float* b_dt   = (const float*)d_in[6];
    const float* W_out  = (const float*)d_in[7];
    const float* A_log  = (const float*)d_in[8];
    const float* Dp     = (const float*)d_in[9];
    float* out = (float*)d_out;

    // ---- workspace layout (~161 MB total, lifetime-checked aliasing) -------
    char* ws = (char*)d_ws;
    size_t off = 0;
    auto alloc = [&](size_t bytes) {
        char* p = ws + off;
        off += (bytes + 255) & ~(size_t)255;
        return (void*)p;
    };
    bf16*  xzb   = (bf16*) alloc((size_t)NROWS * 4096 * 2);   // 64 MB; x_inner half reused as U
    bf16*  xc    = (bf16*) alloc((size_t)NROWS * 2048 * 2);   // 32 MB
    bf16*  dtb   = (bf16*) alloc((size_t)NROWS * 2048 * 2);   // 32 MB; first 8 MB aliased by WinT
    float* bdt   = (float*)alloc((size_t)NROWS * 128 * 4);    //  4 MB
    bf16*  WcombT= (bf16*) alloc((size_t)2176 * 2048 * 2);    //  8.5 MB (W_dt^T ++ W_x^T pad128)
    bf16*  WoutT = (bf16*) alloc((size_t)1024 * 2048 * 2);    //  4 MB
    char*  scr   = (char*) alloc((size_t)16 << 20);           // 16 MB shared scratch
    // aliases (lifetimes verified):
    bf16*  WinT = (bf16*)dtb;          // used only by GEMM1; dt written later by merged GEMM
    bf16*  x_bf = (bf16*)scr;          // used only by GEMM1 (16 MB)
    float* Pb   = (float*)scr;         // written in pass1 (8 MB), after GEMM1
    float* Sb   = (float*)(scr + ((size_t)8 << 20));  // 8 MB
    float* Hb   = Pb;                  // pass2 writes Hinit in-place over P
    bf16*  U    = xzb;                 // pass3 writes U over dead x_inner half

    // ---- weight prep (bf16, transposed to N x K) ---------------------------
    transpose_cast<<<dim3(4096/32, 1024/32), dim3(32, 8), 0, stream>>>(W_in,  WinT,  1024, 4096, 4096);
    transpose_cast<<<dim3(2048/32, 2048/32), dim3(32, 8), 0, stream>>>(W_dt,  WcombT, 2048, 2048, 2048);
    transpose_cast<<<dim3( 128/32, 2048/32), dim3(32, 8), 0, stream>>>(W_x,   WcombT + (size_t)2048 * 2048, 2048, 32, 128);
    transpose_cast<<<dim3(1024/32, 2048/32), dim3(32, 8), 0, stream>>>(W_out, WoutT, 2048, 1024, 1024);
    cast_to_bf16<<<(NROWS * 1024 / 4) / 256, 256, 0, stream>>>(x, x_bf, NROWS * 1024 / 4);

    // xz = x @ W_in  (bf16 out, row stride 4096)
    gemm_bt<2><<<dim3(4096/128, NROWS/128), 256, 0, stream>>>(x_bf, 1024, WinT, 1024, nullptr, xzb, 4096, nullptr, 1024);
    // xc = silu(causal_conv(x_inner) + b)
    conv_silu<<<(NROWS * 256) / 256, 256, 0, stream>>>(xzb, conv_w, conv_b, xc);
    // merged: dt = softplus(xc @ W_dt + b_dt) [cols 0..2047, bf16]
    //         bdt = xc @ W_x                  [cols 2048..2175 -> fp32, ld 128]
    gemm_bt<3><<<dim3(2176/128, NROWS/128), 256, 0, stream>>>(xc, 2048, WcombT, 2048, bdt, dtb, 2048, b_dt, 2048);
    // chunked selective scan
    scan_pass1<<<dim3(DINNER/256, NCHUNK, NBATCH), 256, 0, stream>>>(xc, dtb, bdt, A_log, Pb, Sb);
    scan_pass2<<<(NBATCH * DINNER * 16) / 256, 256, 0, stream>>>(Pb, Sb, Hb);
    scan_pass3<<<dim3(DINNER/256, NCHUNK, NBATCH), 256, 0, stream>>>(xc, dtb, bdt, A_log, Hb, xzb, Dp, U);
    // out = U @ W_out  (U row stride 4096)
    gemm_bt<0><<<dim3(1024/128, NROWS/128), 256, 0, stream>>>(U, 4096, WoutT, 2048, out, nullptr, 1024, nullptr, 2048);
}

// Round 4
// 759.104 us; speedup vs baseline: 1.0143x; 1.0143x over previous
//
#include <hip/hip_runtime.h>
#include <hip/hip_bf16.h>

typedef __hip_bfloat16 bf16;
typedef __attribute__((ext_vector_type(8))) short bf16x8;
typedef __attribute__((ext_vector_type(4))) float f32x4;

#define SEQ     2048
#define DMODEL  1024
#define DINNER  2048
#define NBATCH  4
#define NROWS   (NBATCH * SEQ)   // 8192
#define DSTATE  16
#define NCHUNK  16
#define CHUNK   128              // SEQ / NCHUNK

__device__ __forceinline__ float b2f(short s) {
    union { unsigned u; float f; } c;
    c.u = ((unsigned)(unsigned short)s) << 16;
    return c.f;
}

// async global->LDS, 16B per lane; LDS dest = base + lane*16 (wave-uniform base)
__device__ __forceinline__ void async16(const bf16* g, bf16* l) {
    __builtin_amdgcn_global_load_lds(
        (const __attribute__((address_space(1))) void*)g,
        (__attribute__((address_space(3))) void*)l, 16, 0, 0);
}

// ---------------------------------------------------------------------------
// Transpose + cast fp32 (K x N) -> bf16 (Npad x K), zero-filling rows >= N.
// ---------------------------------------------------------------------------
__global__ __launch_bounds__(256)
void transpose_cast(const float* __restrict__ W, bf16* __restrict__ WT,
                    int K, int N, int Npad)
{
    __shared__ float tile[32][33];
    const int bx = blockIdx.x;            // along N (padded)
    const int by = blockIdx.y;            // along K
    const int tx = threadIdx.x, ty = threadIdx.y;
    const int x = bx * 32 + tx;           // N index
#pragma unroll
    for (int i = 0; i < 32; i += 8) {
        int y = by * 32 + ty + i;         // K index
        tile[ty + i][tx] = (x < N && y < K) ? W[(size_t)y * N + x] : 0.f;
    }
    __syncthreads();
    const int k = by * 32 + tx;
#pragma unroll
    for (int i = 0; i < 32; i += 8) {
        int n = bx * 32 + ty + i;
        if (n < Npad && k < K)
            WT[(size_t)n * K + k] = __float2bfloat16(tile[tx][ty + i]);
    }
}

// ---------------------------------------------------------------------------
// Elementwise fp32 -> bf16 cast
// ---------------------------------------------------------------------------
__global__ __launch_bounds__(256)
void cast_to_bf16(const float* __restrict__ in, bf16* __restrict__ out, int n4)
{
    int i = blockIdx.x * 256 + threadIdx.x;
    if (i < n4) {
        float4 v = *(const float4*)(in + (size_t)i * 4);
        __align__(8) bf16 o[4] = { __float2bfloat16(v.x), __float2bfloat16(v.y),
                                   __float2bfloat16(v.z), __float2bfloat16(v.w) };
        *(uint2*)(out + (size_t)i * 4) = *(uint2*)o;
    }
}

// ---------------------------------------------------------------------------
// GEMM: C[M,N] = A[M,K] @ B^T[N,K]   (bf16 in, fp32 accum).
// A row stride lda, BT row stride ldb, C row stride ldc.
// MODE 0: store fp32.  MODE 2: store bf16.
// MODE 3: merged dt/bdt epilogue — col <  DINNER: bf16 softplus(acc+bias[col])
//                                  col >= DINNER: fp32 to Cf[row*128+col-DINNER]
// 128x128 tile, BK=32, 256 threads (4 waves, 64x64 each, 4x4 MFMA tiles).
// Staging: global_load_lds width=16 into DOUBLE-BUFFERED LDS; prefetch for
// tile k+1 is issued right AFTER the barrier publishing tile k, so the
// barrier's vmcnt(0) drain overlaps a full compute phase (R3 post-mortem:
// issuing then immediately draining exposed full load latency -> 367 TF).
// ---------------------------------------------------------------------------
template <int MODE>
__global__ __launch_bounds__(256, 2)
void gemm_bt(const bf16* __restrict__ A, int lda, const bf16* __restrict__ BT,
             int ldb, float* __restrict__ Cf, bf16* __restrict__ Cb, int ldc,
             const float* __restrict__ bias, int K)
{
    __shared__ __align__(16) bf16 As[2][128 * 32];
    __shared__ __align__(16) bf16 Bs[2][128 * 32];
    const int tid  = threadIdx.x;
    const int lane = tid & 63;
    const int wave = tid >> 6;
    const int m0 = blockIdx.y * 128;
    const int n0 = blockIdx.x * 128;
    const int wm = (wave & 1) * 64;
    const int wn = (wave >> 1) * 64;

    f32x4 acc[4][4];
#pragma unroll
    for (int i = 0; i < 4; ++i)
#pragma unroll
        for (int j = 0; j < 4; ++j) acc[i][j] = (f32x4){0.f, 0.f, 0.f, 0.f};

    // staging geometry: instr (wave,i) covers tile rows [(wave*2+i)*16, +16);
    // lane l -> row l>>2, col chunk (l&3)*8 — contiguous in lane order, which
    // matches the wave-uniform-base + lane*16 LDS scatter of global_load_lds.
    const int r16 = lane >> 2;
    const int cc  = (lane & 3) * 8;
    const bf16* gA0 = A  + (size_t)(m0 + wave * 32 +      r16) * lda + cc;
    const bf16* gA1 = A  + (size_t)(m0 + wave * 32 + 16 + r16) * lda + cc;
    const bf16* gB0 = BT + (size_t)(n0 + wave * 32 +      r16) * ldb + cc;
    const bf16* gB1 = BT + (size_t)(n0 + wave * 32 + 16 + r16) * ldb + cc;
    const int lofs = wave * 1024;        // elems; 2 chunks of 512 per wave

    const int arow = lane & 15;
    const int akq  = (lane >> 4) * 8;
    const int KT = K >> 5;

#define STAGE(buf, kt) do {                                   \
        int _k0 = (kt) * 32;                                  \
        async16(gA0 + _k0, &As[buf][lofs]);                   \
        async16(gA1 + _k0, &As[buf][lofs + 512]);             \
        async16(gB0 + _k0, &Bs[buf][lofs]);                   \
        async16(gB1 + _k0, &Bs[buf][lofs + 512]);             \
    } while (0)

#define COMPUTE(buf) do {                                                     \
        bf16x8 af[4], bfr[4];                                                 \
        _Pragma("unroll")                                                     \
        for (int i = 0; i < 4; ++i)                                           \
            af[i] = *(const bf16x8*)(&As[buf][(wm + i * 16 + arow) * 32 + akq]); \
        _Pragma("unroll")                                                     \
        for (int j = 0; j < 4; ++j)                                           \
            bfr[j] = *(const bf16x8*)(&Bs[buf][(wn + j * 16 + arow) * 32 + akq]); \
        _Pragma("unroll")                                                     \
        for (int i = 0; i < 4; ++i)                                           \
            _Pragma("unroll")                                                 \
            for (int j = 0; j < 4; ++j)                                       \
                acc[i][j] = __builtin_amdgcn_mfma_f32_16x16x32_bf16(          \
                    af[i], bfr[j], acc[i][j], 0, 0, 0);                       \
    } while (0)

    STAGE(0, 0);
    for (int kt = 0; kt < KT; kt += 2) {
        __syncthreads();                    // publishes tile kt (prefetched)
        if (kt + 1 < KT) STAGE(1, kt + 1);  // in flight across compute phase
        COMPUTE(0);
        __syncthreads();                    // publishes tile kt+1; buf0 reads done
        if (kt + 2 < KT) STAGE(0, kt + 2);
        COMPUTE(1);
    }
#undef STAGE
#undef COMPUTE

    // epilogue: C/D layout col = lane&15, row = (lane>>4)*4 + reg
    const int rbase = (lane >> 4) * 4;
    const int cbase = lane & 15;
#pragma unroll
    for (int i = 0; i < 4; ++i) {
        int row = m0 + wm + i * 16 + rbase;
#pragma unroll
        for (int j = 0; j < 4; ++j) {
            int col = n0 + wn + j * 16 + cbase;
#pragma unroll
            for (int r = 0; r < 4; ++r) {
                float v = acc[i][j][r];
                if (MODE == 0) {
                    Cf[(size_t)(row + r) * ldc + col] = v;
                } else if (MODE == 2) {
                    Cb[(size_t)(row + r) * ldc + col] = __float2bfloat16(v);
                } else {   // MODE 3 (uniform per block: n0==2048 -> bdt path)
                    if (col < DINNER) {
                        float v2 = v + bias[col];
                        float sp = (v2 > 20.f) ? v2 : log1pf(__expf(v2));
                        Cb[(size_t)(row + r) * ldc + col] = __float2bfloat16(sp);
                    } else {
                        Cf[(size_t)(row + r) * 128 + (col - DINNER)] = v;
                    }
                }
            }
        }
    }
}

// ---------------------------------------------------------------------------
// Causal depthwise conv (d_conv=4) + bias + SiLU. Reads bf16 x_inner =
// xz[:, :2048] (row stride 4096). One thread per (row, 8 channels).
// ---------------------------------------------------------------------------
__global__ __launch_bounds__(256)
void conv_silu(const bf16* __restrict__ xz, const float* __restrict__ conv_w,
               const float* __restrict__ conv_b, bf16* __restrict__ xc)
{
    int gid = blockIdx.x * 256 + threadIdx.x;   // NROWS * 256
    int d8  = gid & 255;
    int row = gid >> 8;
    int l   = row & (SEQ - 1);
    int d   = d8 * 8;
    const bf16* base = xz + (size_t)row * 4096 + d;
    float acc[8];
    float4 b0 = *(const float4*)(conv_b + d);
    float4 b1 = *(const float4*)(conv_b + d + 4);
    acc[0] = b0.x; acc[1] = b0.y; acc[2] = b0.z; acc[3] = b0.w;
    acc[4] = b1.x; acc[5] = b1.y; acc[6] = b1.z; acc[7] = b1.w;
    float w[8][4];
#pragma unroll
    for (int j = 0; j < 8; ++j) {
        float4 wv = *(const float4*)(conv_w + (size_t)(d + j) * 4);
        w[j][0] = wv.x; w[j][1] = wv.y; w[j][2] = wv.z; w[j][3] = wv.w;
    }
#pragma unroll
    for (int k = 0; k < 4; ++k) {
        if (l + k - 3 >= 0) {   // wave-uniform branch (row is block-uniform)
            bf16x8 v = *(const bf16x8*)(base + (ptrdiff_t)(k - 3) * 4096);
#pragma unroll
            for (int j = 0; j < 8; ++j)
                acc[j] = fmaf(b2f(v[j]), w[j][k], acc[j]);
        }
    }
    __align__(16) bf16 o[8];
#pragma unroll
    for (int j = 0; j < 8; ++j) {
        float s = acc[j] / (1.f + __expf(-acc[j]));
        o[j] = __float2bfloat16(s);
    }
    *(bf16x8*)(xc + (size_t)row * DINNER + d) = *(bf16x8*)o;
}

// ---------------------------------------------------------------------------
// Chunked selective scan, pass 1: per (b, chunk, d): P = prod(a_t), S = local h
// layout P/S[c][b][d][n]
// ---------------------------------------------------------------------------
__global__ __launch_bounds__(256)
void scan_pass1(const bf16* __restrict__ xc, const bf16* __restrict__ dt,
                const float* __restrict__ bdt, const float* __restrict__ A_log,
                float* __restrict__ P, float* __restrict__ S)
{
    const int d  = blockIdx.x * 256 + threadIdx.x;
    const int c  = blockIdx.y;
    const int b  = blockIdx.z;
    const int t0 = c * CHUNK;
    __shared__ float bls[CHUNK][DSTATE];
    for (int i = threadIdx.x; i < CHUNK * DSTATE; i += 256) {
        int tl = i >> 4, col = i & 15;
        bls[tl][col] = bdt[(size_t)(b * SEQ + t0 + tl) * 128 + col];
    }
    __syncthreads();
    float acoef[16], h[16], p[16];
#pragma unroll
    for (int n = 0; n < 16; ++n) {
        acoef[n] = -__expf(A_log[(size_t)d * 16 + n]) * 1.44269504f;
        h[n] = 0.f; p[n] = 1.f;
    }
    size_t idx = (size_t)(b * SEQ + t0) * DINNER + d;
    for (int tl = 0; tl < CHUNK; ++tl, idx += DINNER) {
        float dtv = __bfloat162float(dt[idx]);
        float xv  = __bfloat162float(xc[idx]);
        float u = dtv * xv;
#pragma unroll
        for (int n = 0; n < 16; ++n) {
            float a = exp2f(dtv * acoef[n]);
            p[n] *= a;
            h[n] = fmaf(a, h[n], u * bls[tl][n]);
        }
    }
    size_t o = ((size_t)(c * NBATCH + b) * DINNER + d) * 16;
#pragma unroll
    for (int n = 0; n < 16; n += 4) {
        *(float4*)(P + o + n) = make_float4(p[n], p[n+1], p[n+2], p[n+3]);
        *(float4*)(S + o + n) = make_float4(h[n], h[n+1], h[n+2], h[n+3]);
    }
}

// ---------------------------------------------------------------------------
// Pass 2: sequential combine over chunks. One thread per (b,d,n).
// Hinit may alias P (each element read before overwrite, one owner thread).
// ---------------------------------------------------------------------------
__global__ __launch_bounds__(256)
void scan_pass2(const float* __restrict__ P, const float* __restrict__ S,
                float* __restrict__ Hinit)
{
    size_t idx = (size_t)blockIdx.x * 256 + threadIdx.x;
    const size_t stride = (size_t)NBATCH * DINNER * 16;
    float h = 0.f;
    for (int c = 0; c < NCHUNK; ++c) {
        size_t o = (size_t)c * stride + idx;
        float p = P[o];
        float s = S[o];
        Hinit[o] = h;
        h = fmaf(p, h, s);
    }
}

// ---------------------------------------------------------------------------
// Pass 3: replay chunk from true h_init; fuse y = scan + xc*D, * silu(z),
// cast bf16 into U (row stride 4096; reads z from cols 2048.. of same buffer)
// ---------------------------------------------------------------------------
__global__ __launch_bounds__(256)
void scan_pass3(const bf16* __restrict__ xc, const bf16* __restrict__ dt,
                const float* __restrict__ bdt, const float* __restrict__ A_log,
                const float* __restrict__ Hinit, const bf16* __restrict__ xzb,
                const float* __restrict__ Dp, bf16* __restrict__ U)
{
    const int d  = blockIdx.x * 256 + threadIdx.x;
    const int c  = blockIdx.y;
    const int b  = blockIdx.z;
    const int t0 = c * CHUNK;
    __shared__ float bls[CHUNK][DSTATE];
    __shared__ float cls[CHUNK][DSTATE];
    for (int i = threadIdx.x; i < CHUNK * 32; i += 256) {
        int tl = i >> 5, col = i & 31;
        float v = bdt[(size_t)(b * SEQ + t0 + tl) * 128 + col];
        if (col < 16) bls[tl][col] = v; else cls[tl][col - 16] = v;
    }
    __syncthreads();
    float acoef[16], h[16];
#pragma unroll
    for (int n = 0; n < 16; ++n)
        acoef[n] = -__expf(A_log[(size_t)d * 16 + n]) * 1.44269504f;
    size_t ho = ((size_t)(c * NBATCH + b) * DINNER + d) * 16;
#pragma unroll
    for (int n = 0; n < 16; n += 4) {
        float4 hv = *(const float4*)(Hinit + ho + n);
        h[n] = hv.x; h[n+1] = hv.y; h[n+2] = hv.z; h[n+3] = hv.w;
    }
    const float Dv = Dp[d];
    size_t idx  = (size_t)(b * SEQ + t0) * DINNER + d;
    size_t widx = (size_t)(b * SEQ + t0) * 4096 + d;   // U col d / z col 2048+d
    for (int tl = 0; tl < CHUNK; ++tl, idx += DINNER, widx += 4096) {
        float dtv = __bfloat162float(dt[idx]);
        float xv  = __bfloat162float(xc[idx]);
        float u = dtv * xv;
        float y = 0.f;
#pragma unroll
        for (int n = 0; n < 16; ++n) {
            float a = exp2f(dtv * acoef[n]);
            h[n] = fmaf(a, h[n], u * bls[tl][n]);
            y = fmaf(h[n], cls[tl][n], y);
        }
        float zv = __bfloat162float(xzb[widx + DINNER]);
        float sz = zv / (1.f + __expf(-zv));
        float val = (y + xv * Dv) * sz;
        U[widx] = __float2bfloat16(val);
    }
}

// ---------------------------------------------------------------------------
extern "C" void kernel_launch(void* const* d_in, const int* in_sizes, int n_in,
                              void* d_out, int out_size, void* d_ws, size_t ws_size,
                              hipStream_t stream)
{
    const float* x      = (const float*)d_in[0];
    const float* W_in   = (const float*)d_in[1];
    const float* conv_w = (const float*)d_in[2];
    const float* conv_b = (const float*)d_in[3];
    const float* W_x    = (const float*)d_in[4];
    const float* W_dt   = (const float*)d_in[5];
    const float* b_dt   = (const float*)d_in[6];
    const float* W_out  = (const float*)d_in[7];
    const float* A_log  = (const float*)d_in[8];
    const float* Dp     = (const float*)d_in[9];
    float* out = (float*)d_out;

    // ---- workspace layout (~161 MB total, lifetime-checked aliasing) -------
    char* ws = (char*)d_ws;
    size_t off = 0;
    auto alloc = [&](size_t bytes) {
        char* p = ws + off;
        off += (bytes + 255) & ~(size_t)255;
        return (void*)p;
    };
    bf16*  xzb   = (bf16*) alloc((size_t)NROWS * 4096 * 2);   // 64 MB; x_inner half reused as U
    bf16*  xc    = (bf16*) alloc((size_t)NROWS * 2048 * 2);   // 32 MB
    bf16*  dtb   = (bf16*) alloc((size_t)NROWS * 2048 * 2);   // 32 MB; first 8 MB aliased by WinT
    float* bdt   = (float*)alloc((size_t)NROWS * 128 * 4);    //  4 MB
    bf16*  WcombT= (bf16*) alloc((size_t)2176 * 2048 * 2);    //  8.5 MB (W_dt^T ++ W_x^T pad128)
    bf16*  WoutT = (bf16*) alloc((size_t)1024 * 2048 * 2);    //  4 MB
    char*  scr   = (char*) alloc((size_t)16 << 20);           // 16 MB shared scratch
    // aliases (lifetimes verified):
    bf16*  WinT = (bf16*)dtb;          // used only by GEMM1; dt written later by merged GEMM
    bf16*  x_bf = (bf16*)scr;          // used only by GEMM1 (16 MB)
    float* Pb   = (float*)scr;         // written in pass1 (8 MB), after GEMM1
    float* Sb   = (float*)(scr + ((size_t)8 << 20));  // 8 MB
    float* Hb   = Pb;                  // pass2 writes Hinit in-place over P
    bf16*  U    = xzb;                 // pass3 writes U over dead x_inner half

    // ---- weight prep (bf16, transposed to N x K) ---------------------------
    transpose_cast<<<dim3(4096/32, 1024/32), dim3(32, 8), 0, stream>>>(W_in,  WinT,  1024, 4096, 4096);
    transpose_cast<<<dim3(2048/32, 2048/32), dim3(32, 8), 0, stream>>>(W_dt,  WcombT, 2048, 2048, 2048);
    transpose_cast<<<dim3( 128/32, 2048/32), dim3(32, 8), 0, stream>>>(W_x,   WcombT + (size_t)2048 * 2048, 2048, 32, 128);
    transpose_cast<<<dim3(1024/32, 2048/32), dim3(32, 8), 0, stream>>>(W_out, WoutT, 2048, 1024, 1024);
    cast_to_bf16<<<(NROWS * 1024 / 4) / 256, 256, 0, stream>>>(x, x_bf, NROWS * 1024 / 4);

    // xz = x @ W_in  (bf16 out, row stride 4096)
    gemm_bt<2><<<dim3(4096/128, NROWS/128), 256, 0, stream>>>(x_bf, 1024, WinT, 1024, nullptr, xzb, 4096, nullptr, 1024);
    // xc = silu(causal_conv(x_inner) + b)
    conv_silu<<<(NROWS * 256) / 256, 256, 0, stream>>>(xzb, conv_w, conv_b, xc);
    // merged: dt = softplus(xc @ W_dt + b_dt) [cols 0..2047, bf16]
    //         bdt = xc @ W_x                  [cols 2048..2175 -> fp32, ld 128]
    gemm_bt<3><<<dim3(2176/128, NROWS/128), 256, 0, stream>>>(xc, 2048, WcombT, 2048, bdt, dtb, 2048, b_dt, 2048);
    // chunked selective scan
    scan_pass1<<<dim3(DINNER/256, NCHUNK, NBATCH), 256, 0, stream>>>(xc, dtb, bdt, A_log, Pb, Sb);
    scan_pass2<<<(NBATCH * DINNER * 16) / 256, 256, 0, stream>>>(Pb, Sb, Hb);
    scan_pass3<<<dim3(DINNER/256, NCHUNK, NBATCH), 256, 0, stream>>>(xc, dtb, bdt, A_log, Hb, xzb, Dp, U);
    // out = U @ W_out  (U row stride 4096)
    gemm_bt<0><<<dim3(1024/128, NROWS/128), 256, 0, stream>>>(U, 4096, WoutT, 2048, out, nullptr, 1024, nullptr, 2048);
}

// Round 5
// 739.311 us; speedup vs baseline: 1.0414x; 1.0268x over previous
//
#include <hip/hip_runtime.h>
#include <hip/hip_bf16.h>

typedef __hip_bfloat16 bf16;
typedef __attribute__((ext_vector_type(8))) short bf16x8;
typedef __attribute__((ext_vector_type(4))) float f32x4;

#define SEQ     2048
#define DMODEL  1024
#define DINNER  2048
#define NBATCH  4
#define NROWS   (NBATCH * SEQ)   // 8192
#define DSTATE  16
#define NCHUNK  16
#define CHUNK   128              // SEQ / NCHUNK

__device__ __forceinline__ float b2f(short s) {
    union { unsigned u; float f; } c;
    c.u = ((unsigned)(unsigned short)s) << 16;
    return c.f;
}

// ---------------------------------------------------------------------------
// Transpose + cast fp32 (K x N) -> bf16 (Npad x K), zero-filling rows >= N.
// ---------------------------------------------------------------------------
__global__ __launch_bounds__(256)
void transpose_cast(const float* __restrict__ W, bf16* __restrict__ WT,
                    int K, int N, int Npad)
{
    __shared__ float tile[32][33];
    const int bx = blockIdx.x;            // along N (padded)
    const int by = blockIdx.y;            // along K
    const int tx = threadIdx.x, ty = threadIdx.y;
    const int x = bx * 32 + tx;           // N index
#pragma unroll
    for (int i = 0; i < 32; i += 8) {
        int y = by * 32 + ty + i;         // K index
        tile[ty + i][tx] = (x < N && y < K) ? W[(size_t)y * N + x] : 0.f;
    }
    __syncthreads();
    const int k = by * 32 + tx;
#pragma unroll
    for (int i = 0; i < 32; i += 8) {
        int n = bx * 32 + ty + i;
        if (n < Npad && k < K)
            WT[(size_t)n * K + k] = __float2bfloat16(tile[tx][ty + i]);
    }
}

// ---------------------------------------------------------------------------
// Elementwise fp32 -> bf16 cast
// ---------------------------------------------------------------------------
__global__ __launch_bounds__(256)
void cast_to_bf16(const float* __restrict__ in, bf16* __restrict__ out, int n4)
{
    int i = blockIdx.x * 256 + threadIdx.x;
    if (i < n4) {
        float4 v = *(const float4*)(in + (size_t)i * 4);
        __align__(8) bf16 o[4] = { __float2bfloat16(v.x), __float2bfloat16(v.y),
                                   __float2bfloat16(v.z), __float2bfloat16(v.w) };
        *(uint2*)(out + (size_t)i * 4) = *(uint2*)o;
    }
}

// ---------------------------------------------------------------------------
// GEMM: C[M,N] = A[M,K] @ B^T[N,K]   (bf16 in, fp32 accum).
// A row stride lda, BT row stride ldb, C row stride ldc.
// MODE 0: store fp32.  MODE 2: store bf16.
// MODE 3: merged dt/bdt epilogue — col <  DINNER: bf16 softplus(acc+bias[col])
//                                  col >= DINNER: fp32 to Cf[row*128+col-DINNER]
// 128x128 tile, BK=32, 256 threads (4 waves, 64x64 each, 4x4 MFMA tiles).
// Staging: R2 structure (best measured, 503 TF) — register prefetch of tile
// k+1 issued right after the barrier, ds_write into single-buffered LDS.
// (R3/R4 post-mortem: global_load_lds variants expose full load latency at
// the barrier's vmcnt(0) drain -> 367-400 TF. Registers decouple the global
// load from the barrier; only lgkmcnt is drained.)
// Tile swizzle: group-of-8 m-panels so co-resident blocks share A panels and
// B is re-swept 8x instead of 64x (R4: FETCH 200 MB vs 28 MB ideal).
// ---------------------------------------------------------------------------
template <int MODE>
__global__ __launch_bounds__(256, 2)
void gemm_bt(const bf16* __restrict__ A, int lda, const bf16* __restrict__ BT,
             int ldb, float* __restrict__ Cf, bf16* __restrict__ Cb, int ldc,
             const float* __restrict__ bias, int K)
{
    __shared__ __align__(16) bf16 As[128 * 32];
    __shared__ __align__(16) bf16 Bs[128 * 32];
    const int tid  = threadIdx.x;
    const int lane = tid & 63;
    const int wave = tid >> 6;

    // ---- group-of-8 m-panel swizzle (L2/L3 reuse) ----
    const int gx = gridDim.x, gy = gridDim.y;
    int lin = blockIdx.y * gx + blockIdx.x;
    const int per = 8 * gx;
    int g   = lin / per;
    int rem = lin - g * per;
    int rows = min(8, gy - g * 8);
    const int by = g * 8 + rem % rows;
    const int bx = rem / rows;

    const int m0 = by * 128;
    const int n0 = bx * 128;
    const int wm = (wave & 1) * 64;
    const int wn = (wave >> 1) * 64;

    f32x4 acc[4][4];
#pragma unroll
    for (int i = 0; i < 4; ++i)
#pragma unroll
        for (int j = 0; j < 4; ++j) acc[i][j] = (f32x4){0.f, 0.f, 0.f, 0.f};

    // staging: 512 16B-chunks per tile, 2 per thread
    const int c0 = tid, c1 = tid + 256;
    const int ar0 = c0 >> 2, ac0 = (c0 & 3) * 8;
    const int ar1 = c1 >> 2, ac1 = (c1 & 3) * 8;
    const bf16* pa0 = A  + (size_t)(m0 + ar0) * lda + ac0;
    const bf16* pa1 = A  + (size_t)(m0 + ar1) * lda + ac1;
    const bf16* pb0 = BT + (size_t)(n0 + ar0) * ldb + ac0;
    const bf16* pb1 = BT + (size_t)(n0 + ar1) * ldb + ac1;

    bf16x8 va0 = *(const bf16x8*)pa0;
    bf16x8 va1 = *(const bf16x8*)pa1;
    bf16x8 vb0 = *(const bf16x8*)pb0;
    bf16x8 vb1 = *(const bf16x8*)pb1;

    const int arow = lane & 15;
    const int akq  = (lane >> 4) * 8;
    const int KT = K >> 5;

    for (int kt = 0; kt < KT; ++kt) {
        __syncthreads();   // previous iteration's LDS reads done
        *(bf16x8*)(As + c0 * 8) = va0;
        *(bf16x8*)(As + c1 * 8) = va1;
        *(bf16x8*)(Bs + c0 * 8) = vb0;
        *(bf16x8*)(Bs + c1 * 8) = vb1;
        __syncthreads();
        if (kt + 1 < KT) {          // register prefetch of next tile
            int k0 = (kt + 1) * 32;
            va0 = *(const bf16x8*)(pa0 + k0);
            va1 = *(const bf16x8*)(pa1 + k0);
            vb0 = *(const bf16x8*)(pb0 + k0);
            vb1 = *(const bf16x8*)(pb1 + k0);
        }
        bf16x8 af[4], bfr[4];
#pragma unroll
        for (int i = 0; i < 4; ++i)
            af[i] = *(const bf16x8*)(As + (wm + i * 16 + arow) * 32 + akq);
#pragma unroll
        for (int j = 0; j < 4; ++j)
            bfr[j] = *(const bf16x8*)(Bs + (wn + j * 16 + arow) * 32 + akq);
#pragma unroll
        for (int i = 0; i < 4; ++i)
#pragma unroll
            for (int j = 0; j < 4; ++j)
                acc[i][j] = __builtin_amdgcn_mfma_f32_16x16x32_bf16(
                    af[i], bfr[j], acc[i][j], 0, 0, 0);
    }

    // epilogue: C/D layout col = lane&15, row = (lane>>4)*4 + reg
    const int rbase = (lane >> 4) * 4;
    const int cbase = lane & 15;
#pragma unroll
    for (int i = 0; i < 4; ++i) {
        int row = m0 + wm + i * 16 + rbase;
#pragma unroll
        for (int j = 0; j < 4; ++j) {
            int col = n0 + wn + j * 16 + cbase;
#pragma unroll
            for (int r = 0; r < 4; ++r) {
                float v = acc[i][j][r];
                if (MODE == 0) {
                    Cf[(size_t)(row + r) * ldc + col] = v;
                } else if (MODE == 2) {
                    Cb[(size_t)(row + r) * ldc + col] = __float2bfloat16(v);
                } else {   // MODE 3 (uniform per block: n0==2048 -> bdt path)
                    if (col < DINNER) {
                        float v2 = v + bias[col];
                        float sp = (v2 > 20.f) ? v2 : log1pf(__expf(v2));
                        Cb[(size_t)(row + r) * ldc + col] = __float2bfloat16(sp);
                    } else {
                        Cf[(size_t)(row + r) * 128 + (col - DINNER)] = v;
                    }
                }
            }
        }
    }
}

// ---------------------------------------------------------------------------
// Causal depthwise conv (d_conv=4) + bias + SiLU. Reads bf16 x_inner =
// xz[:, :2048] (row stride 4096). One thread per (row, 8 channels).
// ---------------------------------------------------------------------------
__global__ __launch_bounds__(256)
void conv_silu(const bf16* __restrict__ xz, const float* __restrict__ conv_w,
               const float* __restrict__ conv_b, bf16* __restrict__ xc)
{
    int gid = blockIdx.x * 256 + threadIdx.x;   // NROWS * 256
    int d8  = gid & 255;
    int row = gid >> 8;
    int l   = row & (SEQ - 1);
    int d   = d8 * 8;
    const bf16* base = xz + (size_t)row * 4096 + d;
    float acc[8];
    float4 b0 = *(const float4*)(conv_b + d);
    float4 b1 = *(const float4*)(conv_b + d + 4);
    acc[0] = b0.x; acc[1] = b0.y; acc[2] = b0.z; acc[3] = b0.w;
    acc[4] = b1.x; acc[5] = b1.y; acc[6] = b1.z; acc[7] = b1.w;
    float w[8][4];
#pragma unroll
    for (int j = 0; j < 8; ++j) {
        float4 wv = *(const float4*)(conv_w + (size_t)(d + j) * 4);
        w[j][0] = wv.x; w[j][1] = wv.y; w[j][2] = wv.z; w[j][3] = wv.w;
    }
#pragma unroll
    for (int k = 0; k < 4; ++k) {
        if (l + k - 3 >= 0) {   // wave-uniform branch (row is block-uniform)
            bf16x8 v = *(const bf16x8*)(base + (ptrdiff_t)(k - 3) * 4096);
#pragma unroll
            for (int j = 0; j < 8; ++j)
                acc[j] = fmaf(b2f(v[j]), w[j][k], acc[j]);
        }
    }
    __align__(16) bf16 o[8];
#pragma unroll
    for (int j = 0; j < 8; ++j) {
        float s = acc[j] / (1.f + __expf(-acc[j]));
        o[j] = __float2bfloat16(s);
    }
    *(bf16x8*)(xc + (size_t)row * DINNER + d) = *(bf16x8*)o;
}

// ---------------------------------------------------------------------------
// Chunked selective scan, pass 1: per (b, chunk, d): P = prod(a_t), S = local h
// layout P/S[c][b][d][n]
// ---------------------------------------------------------------------------
__global__ __launch_bounds__(256)
void scan_pass1(const bf16* __restrict__ xc, const bf16* __restrict__ dt,
                const float* __restrict__ bdt, const float* __restrict__ A_log,
                float* __restrict__ P, float* __restrict__ S)
{
    const int d  = blockIdx.x * 256 + threadIdx.x;
    const int c  = blockIdx.y;
    const int b  = blockIdx.z;
    const int t0 = c * CHUNK;
    __shared__ float bls[CHUNK][DSTATE];
    for (int i = threadIdx.x; i < CHUNK * DSTATE; i += 256) {
        int tl = i >> 4, col = i & 15;
        bls[tl][col] = bdt[(size_t)(b * SEQ + t0 + tl) * 128 + col];
    }
    __syncthreads();
    float acoef[16], h[16], p[16];
#pragma unroll
    for (int n = 0; n < 16; ++n) {
        acoef[n] = -__expf(A_log[(size_t)d * 16 + n]) * 1.44269504f;
        h[n] = 0.f; p[n] = 1.f;
    }
    size_t idx = (size_t)(b * SEQ + t0) * DINNER + d;
    for (int tl = 0; tl < CHUNK; ++tl, idx += DINNER) {
        float dtv = __bfloat162float(dt[idx]);
        float xv  = __bfloat162float(xc[idx]);
        float u = dtv * xv;
#pragma unroll
        for (int n = 0; n < 16; ++n) {
            float a = exp2f(dtv * acoef[n]);
            p[n] *= a;
            h[n] = fmaf(a, h[n], u * bls[tl][n]);
        }
    }
    size_t o = ((size_t)(c * NBATCH + b) * DINNER + d) * 16;
#pragma unroll
    for (int n = 0; n < 16; n += 4) {
        *(float4*)(P + o + n) = make_float4(p[n], p[n+1], p[n+2], p[n+3]);
        *(float4*)(S + o + n) = make_float4(h[n], h[n+1], h[n+2], h[n+3]);
    }
}

// ---------------------------------------------------------------------------
// Pass 2: sequential combine over chunks. One thread per (b,d,n).
// Hinit may alias P (each element read before overwrite, one owner thread).
// ---------------------------------------------------------------------------
__global__ __launch_bounds__(256)
void scan_pass2(const float* __restrict__ P, const float* __restrict__ S,
                float* __restrict__ Hinit)
{
    size_t idx = (size_t)blockIdx.x * 256 + threadIdx.x;
    const size_t stride = (size_t)NBATCH * DINNER * 16;
    float h = 0.f;
    for (int c = 0; c < NCHUNK; ++c) {
        size_t o = (size_t)c * stride + idx;
        float p = P[o];
        float s = S[o];
        Hinit[o] = h;
        h = fmaf(p, h, s);
    }
}

// ---------------------------------------------------------------------------
// Pass 3: replay chunk from true h_init; fuse y = scan + xc*D, * silu(z),
// cast bf16 into U (row stride 4096; reads z from cols 2048.. of same buffer)
// ---------------------------------------------------------------------------
__global__ __launch_bounds__(256)
void scan_pass3(const bf16* __restrict__ xc, const bf16* __restrict__ dt,
                const float* __restrict__ bdt, const float* __restrict__ A_log,
                const float* __restrict__ Hinit, const bf16* __restrict__ xzb,
                const float* __restrict__ Dp, bf16* __restrict__ U)
{
    const int d  = blockIdx.x * 256 + threadIdx.x;
    const int c  = blockIdx.y;
    const int b  = blockIdx.z;
    const int t0 = c * CHUNK;
    __shared__ float bls[CHUNK][DSTATE];
    __shared__ float cls[CHUNK][DSTATE];
    for (int i = threadIdx.x; i < CHUNK * 32; i += 256) {
        int tl = i >> 5, col = i & 31;
        float v = bdt[(size_t)(b * SEQ + t0 + tl) * 128 + col];
        if (col < 16) bls[tl][col] = v; else cls[tl][col - 16] = v;
    }
    __syncthreads();
    float acoef[16], h[16];
#pragma unroll
    for (int n = 0; n < 16; ++n)
        acoef[n] = -__expf(A_log[(size_t)d * 16 + n]) * 1.44269504f;
    size_t ho = ((size_t)(c * NBATCH + b) * DINNER + d) * 16;
#pragma unroll
    for (int n = 0; n < 16; n += 4) {
        float4 hv = *(const float4*)(Hinit + ho + n);
        h[n] = hv.x; h[n+1] = hv.y; h[n+2] = hv.z; h[n+3] = hv.w;
    }
    const float Dv = Dp[d];
    size_t idx  = (size_t)(b * SEQ + t0) * DINNER + d;
    size_t widx = (size_t)(b * SEQ + t0) * 4096 + d;   // U col d / z col 2048+d
    for (int tl = 0; tl < CHUNK; ++tl, idx += DINNER, widx += 4096) {
        float dtv = __bfloat162float(dt[idx]);
        float xv  = __bfloat162float(xc[idx]);
        float u = dtv * xv;
        float y = 0.f;
#pragma unroll
        for (int n = 0; n < 16; ++n) {
            float a = exp2f(dtv * acoef[n]);
            h[n] = fmaf(a, h[n], u * bls[tl][n]);
            y = fmaf(h[n], cls[tl][n], y);
        }
        float zv = __bfloat162float(xzb[widx + DINNER]);
        float sz = zv / (1.f + __expf(-zv));
        float val = (y + xv * Dv) * sz;
        U[widx] = __float2bfloat16(val);
    }
}

// ---------------------------------------------------------------------------
extern "C" void kernel_launch(void* const* d_in, const int* in_sizes, int n_in,
                              void* d_out, int out_size, void* d_ws, size_t ws_size,
                              hipStream_t stream)
{
    const float* x      = (const float*)d_in[0];
    const float* W_in   = (const float*)d_in[1];
    const float* conv_w = (const float*)d_in[2];
    const float* conv_b = (const float*)d_in[3];
    const float* W_x    = (const float*)d_in[4];
    const float* W_dt   = (const float*)d_in[5];
    const float* b_dt   = (const float*)d_in[6];
    const float* W_out  = (const float*)d_in[7];
    const float* A_log  = (const float*)d_in[8];
    const float* Dp     = (const float*)d_in[9];
    float* out = (float*)d_out;

    // ---- workspace layout (~161 MB total, lifetime-checked aliasing) -------
    char* ws = (char*)d_ws;
    size_t off = 0;
    auto alloc = [&](size_t bytes) {
        char* p = ws + off;
        off += (bytes + 255) & ~(size_t)255;
        return (void*)p;
    };
    bf16*  xzb   = (bf16*) alloc((size_t)NROWS * 4096 * 2);   // 64 MB; x_inner half reused as U
    bf16*  xc    = (bf16*) alloc((size_t)NROWS * 2048 * 2);   // 32 MB
    bf16*  dtb   = (bf16*) alloc((size_t)NROWS * 2048 * 2);   // 32 MB; first 8 MB aliased by WinT
    float* bdt   = (float*)alloc((size_t)NROWS * 128 * 4);    //  4 MB
    bf16*  WcombT= (bf16*) alloc((size_t)2176 * 2048 * 2);    //  8.5 MB (W_dt^T ++ W_x^T pad128)
    bf16*  WoutT = (bf16*) alloc((size_t)1024 * 2048 * 2);    //  4 MB
    char*  scr   = (char*) alloc((size_t)16 << 20);           // 16 MB shared scratch
    // aliases (lifetimes verified):
    bf16*  WinT = (bf16*)dtb;          // used only by GEMM1; dt written later by merged GEMM
    bf16*  x_bf = (bf16*)scr;          // used only by GEMM1 (16 MB)
    float* Pb   = (float*)scr;         // written in pass1 (8 MB), after GEMM1
    float* Sb   = (float*)(scr + ((size_t)8 << 20));  // 8 MB
    float* Hb   = Pb;                  // pass2 writes Hinit in-place over P
    bf16*  U    = xzb;                 // pass3 writes U over dead x_inner half

    // ---- weight prep (bf16, transposed to N x K) ---------------------------
    transpose_cast<<<dim3(4096/32, 1024/32), dim3(32, 8), 0, stream>>>(W_in,  WinT,  1024, 4096, 4096);
    transpose_cast<<<dim3(2048/32, 2048/32), dim3(32, 8), 0, stream>>>(W_dt,  WcombT, 2048, 2048, 2048);
    transpose_cast<<<dim3( 128/32, 2048/32), dim3(32, 8), 0, stream>>>(W_x,   WcombT + (size_t)2048 * 2048, 2048, 32, 128);
    transpose_cast<<<dim3(1024/32, 2048/32), dim3(32, 8), 0, stream>>>(W_out, WoutT, 2048, 1024, 1024);
    cast_to_bf16<<<(NROWS * 1024 / 4) / 256, 256, 0, stream>>>(x, x_bf, NROWS * 1024 / 4);

    // xz = x @ W_in  (bf16 out, row stride 4096)
    gemm_bt<2><<<dim3(4096/128, NROWS/128), 256, 0, stream>>>(x_bf, 1024, WinT, 1024, nullptr, xzb, 4096, nullptr, 1024);
    // xc = silu(causal_conv(x_inner) + b)
    conv_silu<<<(NROWS * 256) / 256, 256, 0, stream>>>(xzb, conv_w, conv_b, xc);
    // merged: dt = softplus(xc @ W_dt + b_dt) [cols 0..2047, bf16]
    //         bdt = xc @ W_x                  [cols 2048..2175 -> fp32, ld 128]
    gemm_bt<3><<<dim3(2176/128, NROWS/128), 256, 0, stream>>>(xc, 2048, WcombT, 2048, bdt, dtb, 2048, b_dt, 2048);
    // chunked selective scan
    scan_pass1<<<dim3(DINNER/256, NCHUNK, NBATCH), 256, 0, stream>>>(xc, dtb, bdt, A_log, Pb, Sb);
    scan_pass2<<<(NBATCH * DINNER * 16) / 256, 256, 0, stream>>>(Pb, Sb, Hb);
    scan_pass3<<<dim3(DINNER/256, NCHUNK, NBATCH), 256, 0, stream>>>(xc, dtb, bdt, A_log, Hb, xzb, Dp, U);
    // out = U @ W_out  (U row stride 4096)
    gemm_bt<0><<<dim3(1024/128, NROWS/128), 256, 0, stream>>>(U, 4096, WoutT, 2048, out, nullptr, 1024, nullptr, 2048);
}

// Round 6
// 737.332 us; speedup vs baseline: 1.0442x; 1.0027x over previous
//
#include <hip/hip_runtime.h>
#include <hip/hip_bf16.h>

typedef __hip_bfloat16 bf16;
typedef __attribute__((ext_vector_type(8))) short bf16x8;
typedef __attribute__((ext_vector_type(4))) float f32x4;

#define SEQ     2048
#define DMODEL  1024
#define DINNER  2048
#define NBATCH  4
#define NROWS   (NBATCH * SEQ)   // 8192
#define DSTATE  16
#define NCHUNK  16
#define CHUNK   128              // SEQ / NCHUNK

__device__ __forceinline__ float b2f(short s) {
    union { unsigned u; float f; } c;
    c.u = ((unsigned)(unsigned short)s) << 16;
    return c.f;
}

// ---------------------------------------------------------------------------
// Transpose + cast fp32 (K x N) -> bf16 (Npad x K), zero-filling rows >= N.
// ---------------------------------------------------------------------------
__global__ __launch_bounds__(256)
void transpose_cast(const float* __restrict__ W, bf16* __restrict__ WT,
                    int K, int N, int Npad)
{
    __shared__ float tile[32][33];
    const int bx = blockIdx.x;            // along N (padded)
    const int by = blockIdx.y;            // along K
    const int tx = threadIdx.x, ty = threadIdx.y;
    const int x = bx * 32 + tx;           // N index
#pragma unroll
    for (int i = 0; i < 32; i += 8) {
        int y = by * 32 + ty + i;         // K index
        tile[ty + i][tx] = (x < N && y < K) ? W[(size_t)y * N + x] : 0.f;
    }
    __syncthreads();
    const int k = by * 32 + tx;
#pragma unroll
    for (int i = 0; i < 32; i += 8) {
        int n = bx * 32 + ty + i;
        if (n < Npad && k < K)
            WT[(size_t)n * K + k] = __float2bfloat16(tile[tx][ty + i]);
    }
}

// ---------------------------------------------------------------------------
// Elementwise fp32 -> bf16 cast
// ---------------------------------------------------------------------------
__global__ __launch_bounds__(256)
void cast_to_bf16(const float* __restrict__ in, bf16* __restrict__ out, int n4)
{
    int i = blockIdx.x * 256 + threadIdx.x;
    if (i < n4) {
        float4 v = *(const float4*)(in + (size_t)i * 4);
        __align__(8) bf16 o[4] = { __float2bfloat16(v.x), __float2bfloat16(v.y),
                                   __float2bfloat16(v.z), __float2bfloat16(v.w) };
        *(uint2*)(out + (size_t)i * 4) = *(uint2*)o;
    }
}

// ---------------------------------------------------------------------------
// GEMM: C[M,N] = A[M,K] @ B^T[N,K]   (bf16 in, fp32 accum).
// A row stride lda, BT row stride ldb, C row stride ldc.
// MODE 0: store fp32.  MODE 2: store bf16.
// MODE 3: merged dt/bdt epilogue — col <  DINNER: bf16 softplus(acc+bias[col])
//                                  col >= DINNER: fp32 to Cf[row*128+col-DINNER]
// 128x128 tile, BK=64, 256 threads (4 waves, 64x64 each, 4x4 MFMA tiles).
// Staging: register prefetch (R2 structure, best measured) + ds_write into
// XOR-swizzled LDS: element (row,k) stored at slot (k/8)^(row&7) within the
// row's 128B — kills R5's 8.9M SQ_LDS_BANK_CONFLICT (16 lanes of each
// ds_read_b128 previously hit 8 bank-quads; now all 32 banks, 2-way = free).
// BK=64 halves barrier count vs BK=32 and doubles prefetch cover distance.
// Group-of-8 m-panel swizzle kept (R5: FETCH 200->97 MB).
// ---------------------------------------------------------------------------
template <int MODE>
__global__ __launch_bounds__(256, 2)
void gemm_bt(const bf16* __restrict__ A, int lda, const bf16* __restrict__ BT,
             int ldb, float* __restrict__ Cf, bf16* __restrict__ Cb, int ldc,
             const float* __restrict__ bias, int K)
{
    __shared__ __align__(16) bf16 As[128 * 64];
    __shared__ __align__(16) bf16 Bs[128 * 64];
    const int tid  = threadIdx.x;
    const int lane = tid & 63;
    const int wave = tid >> 6;

    // ---- group-of-8 m-panel swizzle (L2/L3 reuse) ----
    const int gx = gridDim.x, gy = gridDim.y;
    int lin = blockIdx.y * gx + blockIdx.x;
    const int per = 8 * gx;
    int g   = lin / per;
    int rem = lin - g * per;
    int rows = min(8, gy - g * 8);
    const int by = g * 8 + rem % rows;
    const int bx = rem / rows;

    const int m0 = by * 128;
    const int n0 = bx * 128;
    const int wm = (wave & 1) * 64;
    const int wn = (wave >> 1) * 64;

    f32x4 acc[4][4];
#pragma unroll
    for (int i = 0; i < 4; ++i)
#pragma unroll
        for (int j = 0; j < 4; ++j) acc[i][j] = (f32x4){0.f, 0.f, 0.f, 0.f};

    // staging: 1024 16B-chunks per matrix per tile, 4 per thread each.
    // chunk c: row=c>>3, logical slot=c&7, stored slot=(c&7)^(row&7).
    int lofs[4];
    const bf16 *pa[4], *pb[4];
#pragma unroll
    for (int i = 0; i < 4; ++i) {
        int c   = tid + 256 * i;
        int row = c >> 3;
        int sl  = c & 7;
        lofs[i] = row * 64 + (sl ^ (row & 7)) * 8;
        pa[i]   = A  + (size_t)(m0 + row) * lda + sl * 8;
        pb[i]   = BT + (size_t)(n0 + row) * ldb + sl * 8;
    }

    bf16x8 va[4], vb[4];
#pragma unroll
    for (int i = 0; i < 4; ++i) { va[i] = *(const bf16x8*)pa[i]; vb[i] = *(const bf16x8*)pb[i]; }

    const int arow = lane & 15;
    const int kq   = lane >> 4;           // 0..3 (8-elem k-quad)
    const int KT   = K >> 6;

    for (int kt = 0; kt < KT; ++kt) {
        __syncthreads();   // previous tile's LDS reads done
#pragma unroll
        for (int i = 0; i < 4; ++i) *(bf16x8*)(As + lofs[i]) = va[i];
#pragma unroll
        for (int i = 0; i < 4; ++i) *(bf16x8*)(Bs + lofs[i]) = vb[i];
        __syncthreads();
        if (kt + 1 < KT) {                // register prefetch of next tile
            int k0 = (kt + 1) * 64;
#pragma unroll
            for (int i = 0; i < 4; ++i) {
                va[i] = *(const bf16x8*)(pa[i] + k0);
                vb[i] = *(const bf16x8*)(pb[i] + k0);
            }
        }
#pragma unroll
        for (int ks = 0; ks < 2; ++ks) {
            bf16x8 af[4], bfr[4];
#pragma unroll
            for (int i = 0; i < 4; ++i) {
                int row = wm + i * 16 + arow;
                af[i] = *(const bf16x8*)(As + row * 64 + ((ks * 4 + kq) ^ (row & 7)) * 8);
            }
#pragma unroll
            for (int j = 0; j < 4; ++j) {
                int row = wn + j * 16 + arow;
                bfr[j] = *(const bf16x8*)(Bs + row * 64 + ((ks * 4 + kq) ^ (row & 7)) * 8);
            }
#pragma unroll
            for (int i = 0; i < 4; ++i)
#pragma unroll
                for (int j = 0; j < 4; ++j)
                    acc[i][j] = __builtin_amdgcn_mfma_f32_16x16x32_bf16(
                        af[i], bfr[j], acc[i][j], 0, 0, 0);
        }
    }

    // epilogue: C/D layout col = lane&15, row = (lane>>4)*4 + reg
    const int rbase = (lane >> 4) * 4;
    const int cbase = lane & 15;
#pragma unroll
    for (int i = 0; i < 4; ++i) {
        int row = m0 + wm + i * 16 + rbase;
#pragma unroll
        for (int j = 0; j < 4; ++j) {
            int col = n0 + wn + j * 16 + cbase;
#pragma unroll
            for (int r = 0; r < 4; ++r) {
                float v = acc[i][j][r];
                if (MODE == 0) {
                    Cf[(size_t)(row + r) * ldc + col] = v;
                } else if (MODE == 2) {
                    Cb[(size_t)(row + r) * ldc + col] = __float2bfloat16(v);
                } else {   // MODE 3 (uniform per block: n0==2048 -> bdt path)
                    if (col < DINNER) {
                        float v2 = v + bias[col];
                        float sp = (v2 > 20.f) ? v2 : log1pf(__expf(v2));
                        Cb[(size_t)(row + r) * ldc + col] = __float2bfloat16(sp);
                    } else {
                        Cf[(size_t)(row + r) * 128 + (col - DINNER)] = v;
                    }
                }
            }
        }
    }
}

// ---------------------------------------------------------------------------
// Causal depthwise conv (d_conv=4) + bias + SiLU. Reads bf16 x_inner =
// xz[:, :2048] (row stride 4096). One thread per (row, 8 channels).
// ---------------------------------------------------------------------------
__global__ __launch_bounds__(256)
void conv_silu(const bf16* __restrict__ xz, const float* __restrict__ conv_w,
               const float* __restrict__ conv_b, bf16* __restrict__ xc)
{
    int gid = blockIdx.x * 256 + threadIdx.x;   // NROWS * 256
    int d8  = gid & 255;
    int row = gid >> 8;
    int l   = row & (SEQ - 1);
    int d   = d8 * 8;
    const bf16* base = xz + (size_t)row * 4096 + d;
    float acc[8];
    float4 b0 = *(const float4*)(conv_b + d);
    float4 b1 = *(const float4*)(conv_b + d + 4);
    acc[0] = b0.x; acc[1] = b0.y; acc[2] = b0.z; acc[3] = b0.w;
    acc[4] = b1.x; acc[5] = b1.y; acc[6] = b1.z; acc[7] = b1.w;
    float w[8][4];
#pragma unroll
    for (int j = 0; j < 8; ++j) {
        float4 wv = *(const float4*)(conv_w + (size_t)(d + j) * 4);
        w[j][0] = wv.x; w[j][1] = wv.y; w[j][2] = wv.z; w[j][3] = wv.w;
    }
#pragma unroll
    for (int k = 0; k < 4; ++k) {
        if (l + k - 3 >= 0) {   // wave-uniform branch (row is block-uniform)
            bf16x8 v = *(const bf16x8*)(base + (ptrdiff_t)(k - 3) * 4096);
#pragma unroll
            for (int j = 0; j < 8; ++j)
                acc[j] = fmaf(b2f(v[j]), w[j][k], acc[j]);
        }
    }
    __align__(16) bf16 o[8];
#pragma unroll
    for (int j = 0; j < 8; ++j) {
        float s = acc[j] / (1.f + __expf(-acc[j]));
        o[j] = __float2bfloat16(s);
    }
    *(bf16x8*)(xc + (size_t)row * DINNER + d) = *(bf16x8*)o;
}

// ---------------------------------------------------------------------------
// Chunked selective scan, pass 1: per (b, chunk, d): P = prod(a_t), S = local h
// layout P/S[c][b][d][n].  dt/xc loads software-pipelined (prefetch t+1).
// ---------------------------------------------------------------------------
__global__ __launch_bounds__(256)
void scan_pass1(const bf16* __restrict__ xc, const bf16* __restrict__ dt,
                const float* __restrict__ bdt, const float* __restrict__ A_log,
                float* __restrict__ P, float* __restrict__ S)
{
    const int d  = blockIdx.x * 256 + threadIdx.x;
    const int c  = blockIdx.y;
    const int b  = blockIdx.z;
    const int t0 = c * CHUNK;
    __shared__ float bls[CHUNK][DSTATE];
    for (int i = threadIdx.x; i < CHUNK * DSTATE; i += 256) {
        int tl = i >> 4, col = i & 15;
        bls[tl][col] = bdt[(size_t)(b * SEQ + t0 + tl) * 128 + col];
    }
    __syncthreads();
    float acoef[16], h[16], p[16];
#pragma unroll
    for (int n = 0; n < 16; ++n) {
        acoef[n] = -__expf(A_log[(size_t)d * 16 + n]) * 1.44269504f;
        h[n] = 0.f; p[n] = 1.f;
    }
    size_t idx = (size_t)(b * SEQ + t0) * DINNER + d;
    bf16 dcur = dt[idx], xcur = xc[idx];
    for (int tl = 0; tl < CHUNK; ++tl) {
        bf16 dnext = dcur, xnext = xcur;
        if (tl + 1 < CHUNK) {                 // prefetch next timestep
            dnext = dt[idx + DINNER];
            xnext = xc[idx + DINNER];
        }
        float dtv = __bfloat162float(dcur);
        float xv  = __bfloat162float(xcur);
        float u = dtv * xv;
#pragma unroll
        for (int n = 0; n < 16; ++n) {
            float a = exp2f(dtv * acoef[n]);
            p[n] *= a;
            h[n] = fmaf(a, h[n], u * bls[tl][n]);
        }
        dcur = dnext; xcur = xnext; idx += DINNER;
    }
    size_t o = ((size_t)(c * NBATCH + b) * DINNER + d) * 16;
#pragma unroll
    for (int n = 0; n < 16; n += 4) {
        *(float4*)(P + o + n) = make_float4(p[n], p[n+1], p[n+2], p[n+3]);
        *(float4*)(S + o + n) = make_float4(h[n], h[n+1], h[n+2], h[n+3]);
    }
}

// ---------------------------------------------------------------------------
// Pass 2: sequential combine over chunks. One thread per (b,d,n).
// Hinit may alias P (each element read before overwrite, one owner thread).
// ---------------------------------------------------------------------------
__global__ __launch_bounds__(256)
void scan_pass2(const float* __restrict__ P, const float* __restrict__ S,
                float* __restrict__ Hinit)
{
    size_t idx = (size_t)blockIdx.x * 256 + threadIdx.x;
    const size_t stride = (size_t)NBATCH * DINNER * 16;
    float h = 0.f;
    for (int c = 0; c < NCHUNK; ++c) {
        size_t o = (size_t)c * stride + idx;
        float p = P[o];
        float s = S[o];
        Hinit[o] = h;
        h = fmaf(p, h, s);
    }
}

// ---------------------------------------------------------------------------
// Pass 3: replay chunk from true h_init; fuse y = scan + xc*D, * silu(z),
// cast bf16 into U (row stride 4096; reads z from cols 2048.. of same buffer).
// dt/xc/z loads software-pipelined (prefetch t+1).
// ---------------------------------------------------------------------------
__global__ __launch_bounds__(256)
void scan_pass3(const bf16* __restrict__ xc, const bf16* __restrict__ dt,
                const float* __restrict__ bdt, const float* __restrict__ A_log,
                const float* __restrict__ Hinit, const bf16* __restrict__ xzb,
                const float* __restrict__ Dp, bf16* __restrict__ U)
{
    const int d  = blockIdx.x * 256 + threadIdx.x;
    const int c  = blockIdx.y;
    const int b  = blockIdx.z;
    const int t0 = c * CHUNK;
    __shared__ float bls[CHUNK][DSTATE];
    __shared__ float cls[CHUNK][DSTATE];
    for (int i = threadIdx.x; i < CHUNK * 32; i += 256) {
        int tl = i >> 5, col = i & 31;
        float v = bdt[(size_t)(b * SEQ + t0 + tl) * 128 + col];
        if (col < 16) bls[tl][col] = v; else cls[tl][col - 16] = v;
    }
    __syncthreads();
    float acoef[16], h[16];
#pragma unroll
    for (int n = 0; n < 16; ++n)
        acoef[n] = -__expf(A_log[(size_t)d * 16 + n]) * 1.44269504f;
    size_t ho = ((size_t)(c * NBATCH + b) * DINNER + d) * 16;
#pragma unroll
    for (int n = 0; n < 16; n += 4) {
        float4 hv = *(const float4*)(Hinit + ho + n);
        h[n] = hv.x; h[n+1] = hv.y; h[n+2] = hv.z; h[n+3] = hv.w;
    }
    const float Dv = Dp[d];
    size_t idx  = (size_t)(b * SEQ + t0) * DINNER + d;
    size_t widx = (size_t)(b * SEQ + t0) * 4096 + d;   // U col d / z col 2048+d
    bf16 dcur = dt[idx], xcur = xc[idx], zcur = xzb[widx + DINNER];
    for (int tl = 0; tl < CHUNK; ++tl) {
        bf16 dnext = dcur, xnext = xcur, znext = zcur;
        if (tl + 1 < CHUNK) {                 // prefetch next timestep
            dnext = dt[idx + DINNER];
            xnext = xc[idx + DINNER];
            znext = xzb[widx + 4096 + DINNER];
        }
        float dtv = __bfloat162float(dcur);
        float xv  = __bfloat162float(xcur);
        float u = dtv * xv;
        float y = 0.f;
#pragma unroll
        for (int n = 0; n < 16; ++n) {
            float a = exp2f(dtv * acoef[n]);
            h[n] = fmaf(a, h[n], u * bls[tl][n]);
            y = fmaf(h[n], cls[tl][n], y);
        }
        float zv = __bfloat162float(zcur);
        float sz = zv / (1.f + __expf(-zv));
        float val = (y + xv * Dv) * sz;
        U[widx] = __float2bfloat16(val);
        dcur = dnext; xcur = xnext; zcur = znext;
        idx += DINNER; widx += 4096;
    }
}

// ---------------------------------------------------------------------------
extern "C" void kernel_launch(void* const* d_in, const int* in_sizes, int n_in,
                              void* d_out, int out_size, void* d_ws, size_t ws_size,
                              hipStream_t stream)
{
    const float* x      = (const float*)d_in[0];
    const float* W_in   = (const float*)d_in[1];
    const float* conv_w = (const float*)d_in[2];
    const float* conv_b = (const float*)d_in[3];
    const float* W_x    = (const float*)d_in[4];
    const float* W_dt   = (const float*)d_in[5];
    const float* b_dt   = (const float*)d_in[6];
    const float* W_out  = (const float*)d_in[7];
    const float* A_log  = (const float*)d_in[8];
    const float* Dp     = (const float*)d_in[9];
    float* out = (float*)d_out;

    // ---- workspace layout (~161 MB total, lifetime-checked aliasing) -------
    char* ws = (char*)d_ws;
    size_t off = 0;
    auto alloc = [&](size_t bytes) {
        char* p = ws + off;
        off += (bytes + 255) & ~(size_t)255;
        return (void*)p;
    };
    bf16*  xzb   = (bf16*) alloc((size_t)NROWS * 4096 * 2);   // 64 MB; x_inner half reused as U
    bf16*  xc    = (bf16*) alloc((size_t)NROWS * 2048 * 2);   // 32 MB
    bf16*  dtb   = (bf16*) alloc((size_t)NROWS * 2048 * 2);   // 32 MB; first 8 MB aliased by WinT
    float* bdt   = (float*)alloc((size_t)NROWS * 128 * 4);    //  4 MB
    bf16*  WcombT= (bf16*) alloc((size_t)2176 * 2048 * 2);    //  8.5 MB (W_dt^T ++ W_x^T pad128)
    bf16*  WoutT = (bf16*) alloc((size_t)1024 * 2048 * 2);    //  4 MB
    char*  scr   = (char*) alloc((size_t)16 << 20);           // 16 MB shared scratch
    // aliases (lifetimes verified):
    bf16*  WinT = (bf16*)dtb;          // used only by GEMM1; dt written later by merged GEMM
    bf16*  x_bf = (bf16*)scr;          // used only by GEMM1 (16 MB)
    float* Pb   = (float*)scr;         // written in pass1 (8 MB), after GEMM1
    float* Sb   = (float*)(scr + ((size_t)8 << 20));  // 8 MB
    float* Hb   = Pb;                  // pass2 writes Hinit in-place over P
    bf16*  U    = xzb;                 // pass3 writes U over dead x_inner half

    // ---- weight prep (bf16, transposed to N x K) ---------------------------
    transpose_cast<<<dim3(4096/32, 1024/32), dim3(32, 8), 0, stream>>>(W_in,  WinT,  1024, 4096, 4096);
    transpose_cast<<<dim3(2048/32, 2048/32), dim3(32, 8), 0, stream>>>(W_dt,  WcombT, 2048, 2048, 2048);
    transpose_cast<<<dim3( 128/32, 2048/32), dim3(32, 8), 0, stream>>>(W_x,   WcombT + (size_t)2048 * 2048, 2048, 32, 128);
    transpose_cast<<<dim3(1024/32, 2048/32), dim3(32, 8), 0, stream>>>(W_out, WoutT, 2048, 1024, 1024);
    cast_to_bf16<<<(NROWS * 1024 / 4) / 256, 256, 0, stream>>>(x, x_bf, NROWS * 1024 / 4);

    // xz = x @ W_in  (bf16 out, row stride 4096)
    gemm_bt<2><<<dim3(4096/128, NROWS/128), 256, 0, stream>>>(x_bf, 1024, WinT, 1024, nullptr, xzb, 4096, nullptr, 1024);
    // xc = silu(causal_conv(x_inner) + b)
    conv_silu<<<(NROWS * 256) / 256, 256, 0, stream>>>(xzb, conv_w, conv_b, xc);
    // merged: dt = softplus(xc @ W_dt + b_dt) [cols 0..2047, bf16]
    //         bdt = xc @ W_x                  [cols 2048..2175 -> fp32, ld 128]
    gemm_bt<3><<<dim3(2176/128, NROWS/128), 256, 0, stream>>>(xc, 2048, WcombT, 2048, bdt, dtb, 2048, b_dt, 2048);
    // chunked selective scan
    scan_pass1<<<dim3(DINNER/256, NCHUNK, NBATCH), 256, 0, stream>>>(xc, dtb, bdt, A_log, Pb, Sb);
    scan_pass2<<<(NBATCH * DINNER * 16) / 256, 256, 0, stream>>>(Pb, Sb, Hb);
    scan_pass3<<<dim3(DINNER/256, NCHUNK, NBATCH), 256, 0, stream>>>(xc, dtb, bdt, A_log, Hb, xzb, Dp, U);
    // out = U @ W_out  (U row stride 4096)
    gemm_bt<0><<<dim3(1024/128, NROWS/128), 256, 0, stream>>>(U, 4096, WoutT, 2048, out, nullptr, 1024, nullptr, 2048);
}

// Round 7
// 689.084 us; speedup vs baseline: 1.1174x; 1.0700x over previous
//
#include <hip/hip_runtime.h>
#include <hip/hip_bf16.h>

typedef __hip_bfloat16 bf16;
typedef __attribute__((ext_vector_type(8))) short bf16x8;
typedef __attribute__((ext_vector_type(4))) float f32x4;

#define SEQ     2048
#define DMODEL  1024
#define DINNER  2048
#define NBATCH  4
#define NROWS   (NBATCH * SEQ)   // 8192
#define DSTATE  16
#define NCHUNK  16
#define CHUNK   128              // SEQ / NCHUNK

__device__ __forceinline__ float b2f(short s) {
    union { unsigned u; float f; } c;
    c.u = ((unsigned)(unsigned short)s) << 16;
    return c.f;
}

// ---------------------------------------------------------------------------
// Fused weight-prep kernel: one dispatch does all 4 transposes + the x cast.
// Job selection by linear block id (block-uniform branches, no divergence).
//   [0,     8192): cast x (fp32->bf16), 4 elems/thread
//   [8192, 12288): W_in  (1024x4096) -> WinT  (4096x1024)
//   [12288,16384): W_dt  (2048x2048) -> WcombT rows 0..2047
//   [16384,16640): W_x   (2048x32)   -> WcombT rows 2048..2175 (pad 128)
//   [16640,18688): W_out (2048x1024) -> WoutT (1024x2048)
// ---------------------------------------------------------------------------
__device__ __forceinline__ void transpose_tile(
    const float* __restrict__ W, bf16* __restrict__ WT,
    int K, int N, int Npad, int bx, int by)
{
    __shared__ float tile[32][33];
    const int tx = threadIdx.x & 31, ty = threadIdx.x >> 5;   // 32 x 8
    const int x = bx * 32 + tx;           // N index
#pragma unroll
    for (int i = 0; i < 32; i += 8) {
        int y = by * 32 + ty + i;         // K index
        tile[ty + i][tx] = (x < N && y < K) ? W[(size_t)y * N + x] : 0.f;
    }
    __syncthreads();
    const int k = by * 32 + tx;
#pragma unroll
    for (int i = 0; i < 32; i += 8) {
        int n = bx * 32 + ty + i;
        if (n < Npad && k < K)
            WT[(size_t)n * K + k] = __float2bfloat16(tile[tx][ty + i]);
    }
}

__global__ __launch_bounds__(256)
void prep(const float* __restrict__ x,     const float* __restrict__ W_in,
          const float* __restrict__ W_dt,  const float* __restrict__ W_x,
          const float* __restrict__ W_out, bf16* __restrict__ x_bf,
          bf16* __restrict__ WinT, bf16* __restrict__ WcombT,
          bf16* __restrict__ WoutT)
{
    const int bid = blockIdx.x;
    if (bid < 8192) {
        int i = bid * 256 + threadIdx.x;          // x cast: 8.4M elems / 4
        float4 v = *(const float4*)(x + (size_t)i * 4);
        __align__(8) bf16 o[4] = { __float2bfloat16(v.x), __float2bfloat16(v.y),
                                   __float2bfloat16(v.z), __float2bfloat16(v.w) };
        *(uint2*)(x_bf + (size_t)i * 4) = *(uint2*)o;
    } else if (bid < 12288) {
        int t = bid - 8192;                       // W_in: 128 x 32 tiles
        transpose_tile(W_in, WinT, 1024, 4096, 4096, t & 127, t >> 7);
    } else if (bid < 16384) {
        int t = bid - 12288;                      // W_dt: 64 x 64 tiles
        transpose_tile(W_dt, WcombT, 2048, 2048, 2048, t & 63, t >> 6);
    } else if (bid < 16640) {
        int t = bid - 16384;                      // W_x: 4 x 64 tiles
        transpose_tile(W_x, WcombT + (size_t)2048 * 2048, 2048, 32, 128,
                       t & 3, t >> 2);
    } else {
        int t = bid - 16640;                      // W_out: 32 x 64 tiles
        transpose_tile(W_out, WoutT, 2048, 1024, 1024, t & 31, t >> 5);
    }
}

// ---------------------------------------------------------------------------
// GEMM: C[M,N] = A[M,K] @ B^T[N,K]   (bf16 in, fp32 accum).
// A row stride lda, BT row stride ldb, C row stride ldc.
// MODE 0: store fp32.  MODE 2: store bf16.
// MODE 3: merged dt/bdt epilogue — col <  DINNER: bf16 softplus(acc+bias[col])
//                                  col >= DINNER: fp32 to Cf[row*128+col-DINNER]
// 128x128 tile, BK=32, 256 threads (4 waves, 64x64 each, 4x4 MFMA tiles).
// Staging: R2-EXACT structure — the measured best across R2..R6 (503 TF):
// register prefetch of tile k+1 issued after the publishing barrier, ds_write
// into single-buffered row-major LDS. Ladder evidence:
//   R2 regprefetch/BK32/row-major . . 503 TF   <-- this
//   R5 + m-panel swizzle + merge  . . 453 TF   (FETCH halved, time ~flat)
//   R4 async dbuf  . . . . . . . . .  400 TF   (vmcnt(0) drain at barrier)
//   R3 async single . . . . . . . . . 367 TF
//   R6 BK64 + XOR LDS swizzle . . . . 308 TF   (conflicts 0 but VGPR 80,
//                                              occupancy/overlap collapse)
// Bank conflicts (8.9M) are NOT on the critical path here; occupancy and
// cross-block overlap are. Do not re-add the swizzles without new evidence.
// ---------------------------------------------------------------------------
template <int MODE>
__global__ __launch_bounds__(256, 2)
void gemm_bt(const bf16* __restrict__ A, int lda, const bf16* __restrict__ BT,
             int ldb, float* __restrict__ Cf, bf16* __restrict__ Cb, int ldc,
             const float* __restrict__ bias, int K)
{
    __shared__ __align__(16) bf16 As[128 * 32];
    __shared__ __align__(16) bf16 Bs[128 * 32];
    const int tid  = threadIdx.x;
    const int lane = tid & 63;
    const int wave = tid >> 6;
    const int m0 = blockIdx.y * 128;
    const int n0 = blockIdx.x * 128;
    const int wm = (wave & 1) * 64;
    const int wn = (wave >> 1) * 64;

    f32x4 acc[4][4];
#pragma unroll
    for (int i = 0; i < 4; ++i)
#pragma unroll
        for (int j = 0; j < 4; ++j) acc[i][j] = (f32x4){0.f, 0.f, 0.f, 0.f};

    // staging: 512 16B-chunks per tile, 2 per thread
    const int c0 = tid, c1 = tid + 256;
    const int ar0 = c0 >> 2, ac0 = (c0 & 3) * 8;
    const int ar1 = c1 >> 2, ac1 = (c1 & 3) * 8;
    const bf16* pa0 = A  + (size_t)(m0 + ar0) * lda + ac0;
    const bf16* pa1 = A  + (size_t)(m0 + ar1) * lda + ac1;
    const bf16* pb0 = BT + (size_t)(n0 + ar0) * ldb + ac0;
    const bf16* pb1 = BT + (size_t)(n0 + ar1) * ldb + ac1;

    bf16x8 va0 = *(const bf16x8*)pa0;
    bf16x8 va1 = *(const bf16x8*)pa1;
    bf16x8 vb0 = *(const bf16x8*)pb0;
    bf16x8 vb1 = *(const bf16x8*)pb1;

    const int arow = lane & 15;
    const int akq  = (lane >> 4) * 8;
    const int KT = K >> 5;

    for (int kt = 0; kt < KT; ++kt) {
        __syncthreads();   // previous iteration's LDS reads done
        *(bf16x8*)(As + c0 * 8) = va0;
        *(bf16x8*)(As + c1 * 8) = va1;
        *(bf16x8*)(Bs + c0 * 8) = vb0;
        *(bf16x8*)(Bs + c1 * 8) = vb1;
        __syncthreads();
        if (kt + 1 < KT) {          // register prefetch of next tile
            int k0 = (kt + 1) * 32;
            va0 = *(const bf16x8*)(pa0 + k0);
            va1 = *(const bf16x8*)(pa1 + k0);
            vb0 = *(const bf16x8*)(pb0 + k0);
            vb1 = *(const bf16x8*)(pb1 + k0);
        }
        bf16x8 af[4], bfr[4];
#pragma unroll
        for (int i = 0; i < 4; ++i)
            af[i] = *(const bf16x8*)(As + (wm + i * 16 + arow) * 32 + akq);
#pragma unroll
        for (int j = 0; j < 4; ++j)
            bfr[j] = *(const bf16x8*)(Bs + (wn + j * 16 + arow) * 32 + akq);
#pragma unroll
        for (int i = 0; i < 4; ++i)
#pragma unroll
            for (int j = 0; j < 4; ++j)
                acc[i][j] = __builtin_amdgcn_mfma_f32_16x16x32_bf16(
                    af[i], bfr[j], acc[i][j], 0, 0, 0);
    }

    // epilogue: C/D layout col = lane&15, row = (lane>>4)*4 + reg
    const int rbase = (lane >> 4) * 4;
    const int cbase = lane & 15;
#pragma unroll
    for (int i = 0; i < 4; ++i) {
        int row = m0 + wm + i * 16 + rbase;
#pragma unroll
        for (int j = 0; j < 4; ++j) {
            int col = n0 + wn + j * 16 + cbase;
#pragma unroll
            for (int r = 0; r < 4; ++r) {
                float v = acc[i][j][r];
                if (MODE == 0) {
                    Cf[(size_t)(row + r) * ldc + col] = v;
                } else if (MODE == 2) {
                    Cb[(size_t)(row + r) * ldc + col] = __float2bfloat16(v);
                } else {   // MODE 3 (uniform per block: n0==2048 -> bdt path)
                    if (col < DINNER) {
                        float v2 = v + bias[col];
                        float sp = (v2 > 20.f) ? v2 : log1pf(__expf(v2));
                        Cb[(size_t)(row + r) * ldc + col] = __float2bfloat16(sp);
                    } else {
                        Cf[(size_t)(row + r) * 128 + (col - DINNER)] = v;
                    }
                }
            }
        }
    }
}

// ---------------------------------------------------------------------------
// Causal depthwise conv (d_conv=4) + bias + SiLU. Reads bf16 x_inner =
// xz[:, :2048] (row stride 4096). One thread per (row, 8 channels).
// ---------------------------------------------------------------------------
__global__ __launch_bounds__(256)
void conv_silu(const bf16* __restrict__ xz, const float* __restrict__ conv_w,
               const float* __restrict__ conv_b, bf16* __restrict__ xc)
{
    int gid = blockIdx.x * 256 + threadIdx.x;   // NROWS * 256
    int d8  = gid & 255;
    int row = gid >> 8;
    int l   = row & (SEQ - 1);
    int d   = d8 * 8;
    const bf16* base = xz + (size_t)row * 4096 + d;
    float acc[8];
    float4 b0 = *(const float4*)(conv_b + d);
    float4 b1 = *(const float4*)(conv_b + d + 4);
    acc[0] = b0.x; acc[1] = b0.y; acc[2] = b0.z; acc[3] = b0.w;
    acc[4] = b1.x; acc[5] = b1.y; acc[6] = b1.z; acc[7] = b1.w;
    float w[8][4];
#pragma unroll
    for (int j = 0; j < 8; ++j) {
        float4 wv = *(const float4*)(conv_w + (size_t)(d + j) * 4);
        w[j][0] = wv.x; w[j][1] = wv.y; w[j][2] = wv.z; w[j][3] = wv.w;
    }
#pragma unroll
    for (int k = 0; k < 4; ++k) {
        if (l + k - 3 >= 0) {   // wave-uniform branch (row is block-uniform)
            bf16x8 v = *(const bf16x8*)(base + (ptrdiff_t)(k - 3) * 4096);
#pragma unroll
            for (int j = 0; j < 8; ++j)
                acc[j] = fmaf(b2f(v[j]), w[j][k], acc[j]);
        }
    }
    __align__(16) bf16 o[8];
#pragma unroll
    for (int j = 0; j < 8; ++j) {
        float s = acc[j] / (1.f + __expf(-acc[j]));
        o[j] = __float2bfloat16(s);
    }
    *(bf16x8*)(xc + (size_t)row * DINNER + d) = *(bf16x8*)o;
}

// ---------------------------------------------------------------------------
// Chunked selective scan, pass 1: per (b, chunk, d): P = prod(a_t), S = local h
// layout P/S[c][b][d][n].  dt/xc loads software-pipelined (prefetch t+1).
// ---------------------------------------------------------------------------
__global__ __launch_bounds__(256)
void scan_pass1(const bf16* __restrict__ xc, const bf16* __restrict__ dt,
                const float* __restrict__ bdt, const float* __restrict__ A_log,
                float* __restrict__ P, float* __restrict__ S)
{
    const int d  = blockIdx.x * 256 + threadIdx.x;
    const int c  = blockIdx.y;
    const int b  = blockIdx.z;
    const int t0 = c * CHUNK;
    __shared__ float bls[CHUNK][DSTATE];
    for (int i = threadIdx.x; i < CHUNK * DSTATE; i += 256) {
        int tl = i >> 4, col = i & 15;
        bls[tl][col] = bdt[(size_t)(b * SEQ + t0 + tl) * 128 + col];
    }
    __syncthreads();
    float acoef[16], h[16], p[16];
#pragma unroll
    for (int n = 0; n < 16; ++n) {
        acoef[n] = -__expf(A_log[(size_t)d * 16 + n]) * 1.44269504f;
        h[n] = 0.f; p[n] = 1.f;
    }
    size_t idx = (size_t)(b * SEQ + t0) * DINNER + d;
    bf16 dcur = dt[idx], xcur = xc[idx];
    for (int tl = 0; tl < CHUNK; ++tl) {
        bf16 dnext = dcur, xnext = xcur;
        if (tl + 1 < CHUNK) {                 // prefetch next timestep
            dnext = dt[idx + DINNER];
            xnext = xc[idx + DINNER];
        }
        float dtv = __bfloat162float(dcur);
        float xv  = __bfloat162float(xcur);
        float u = dtv * xv;
#pragma unroll
        for (int n = 0; n < 16; ++n) {
            float a = exp2f(dtv * acoef[n]);
            p[n] *= a;
            h[n] = fmaf(a, h[n], u * bls[tl][n]);
        }
        dcur = dnext; xcur = xnext; idx += DINNER;
    }
    size_t o = ((size_t)(c * NBATCH + b) * DINNER + d) * 16;
#pragma unroll
    for (int n = 0; n < 16; n += 4) {
        *(float4*)(P + o + n) = make_float4(p[n], p[n+1], p[n+2], p[n+3]);
        *(float4*)(S + o + n) = make_float4(h[n], h[n+1], h[n+2], h[n+3]);
    }
}

// ---------------------------------------------------------------------------
// Pass 2: sequential combine over chunks. One thread per (b,d,n).
// Hinit may alias P (each element read before overwrite, one owner thread).
// ---------------------------------------------------------------------------
__global__ __launch_bounds__(256)
void scan_pass2(const float* __restrict__ P, const float* __restrict__ S,
                float* __restrict__ Hinit)
{
    size_t idx = (size_t)blockIdx.x * 256 + threadIdx.x;
    const size_t stride = (size_t)NBATCH * DINNER * 16;
    float h = 0.f;
    for (int c = 0; c < NCHUNK; ++c) {
        size_t o = (size_t)c * stride + idx;
        float p = P[o];
        float s = S[o];
        Hinit[o] = h;
        h = fmaf(p, h, s);
    }
}

// ---------------------------------------------------------------------------
// Pass 3: replay chunk from true h_init; fuse y = scan + xc*D, * silu(z),
// cast bf16 into U (row stride 4096; reads z from cols 2048.. of same buffer).
// dt/xc/z loads software-pipelined (prefetch t+1).
// ---------------------------------------------------------------------------
__global__ __launch_bounds__(256)
void scan_pass3(const bf16* __restrict__ xc, const bf16* __restrict__ dt,
                const float* __restrict__ bdt, const float* __restrict__ A_log,
                const float* __restrict__ Hinit, const bf16* __restrict__ xzb,
                const float* __restrict__ Dp, bf16* __restrict__ U)
{
    const int d  = blockIdx.x * 256 + threadIdx.x;
    const int c  = blockIdx.y;
    const int b  = blockIdx.z;
    const int t0 = c * CHUNK;
    __shared__ float bls[CHUNK][DSTATE];
    __shared__ float cls[CHUNK][DSTATE];
    for (int i = threadIdx.x; i < CHUNK * 32; i += 256) {
        int tl = i >> 5, col = i & 31;
        float v = bdt[(size_t)(b * SEQ + t0 + tl) * 128 + col];
        if (col < 16) bls[tl][col] = v; else cls[tl][col - 16] = v;
    }
    __syncthreads();
    float acoef[16], h[16];
#pragma unroll
    for (int n = 0; n < 16; ++n)
        acoef[n] = -__expf(A_log[(size_t)d * 16 + n]) * 1.44269504f;
    size_t ho = ((size_t)(c * NBATCH + b) * DINNER + d) * 16;
#pragma unroll
    for (int n = 0; n < 16; n += 4) {
        float4 hv = *(const float4*)(Hinit + ho + n);
        h[n] = hv.x; h[n+1] = hv.y; h[n+2] = hv.z; h[n+3] = hv.w;
    }
    const float Dv = Dp[d];
    size_t idx  = (size_t)(b * SEQ + t0) * DINNER + d;
    size_t widx = (size_t)(b * SEQ + t0) * 4096 + d;   // U col d / z col 2048+d
    bf16 dcur = dt[idx], xcur = xc[idx], zcur = xzb[widx + DINNER];
    for (int tl = 0; tl < CHUNK; ++tl) {
        bf16 dnext = dcur, xnext = xcur, znext = zcur;
        if (tl + 1 < CHUNK) {                 // prefetch next timestep
            dnext = dt[idx + DINNER];
            xnext = xc[idx + DINNER];
            znext = xzb[widx + 4096 + DINNER];
        }
        float dtv = __bfloat162float(dcur);
        float xv  = __bfloat162float(xcur);
        float u = dtv * xv;
        float y = 0.f;
#pragma unroll
        for (int n = 0; n < 16; ++n) {
            float a = exp2f(dtv * acoef[n]);
            h[n] = fmaf(a, h[n], u * bls[tl][n]);
            y = fmaf(h[n], cls[tl][n], y);
        }
        float zv = __bfloat162float(zcur);
        float sz = zv / (1.f + __expf(-zv));
        float val = (y + xv * Dv) * sz;
        U[widx] = __float2bfloat16(val);
        dcur = dnext; xcur = xnext; zcur = znext;
        idx += DINNER; widx += 4096;
    }
}

// ---------------------------------------------------------------------------
extern "C" void kernel_launch(void* const* d_in, const int* in_sizes, int n_in,
                              void* d_out, int out_size, void* d_ws, size_t ws_size,
                              hipStream_t stream)
{
    const float* x      = (const float*)d_in[0];
    const float* W_in   = (const float*)d_in[1];
    const float* conv_w = (const float*)d_in[2];
    const float* conv_b = (const float*)d_in[3];
    const float* W_x    = (const float*)d_in[4];
    const float* W_dt   = (const float*)d_in[5];
    const float* b_dt   = (const float*)d_in[6];
    const float* W_out  = (const float*)d_in[7];
    const float* A_log  = (const float*)d_in[8];
    const float* Dp     = (const float*)d_in[9];
    float* out = (float*)d_out;

    // ---- workspace layout (~161 MB total, lifetime-checked aliasing) -------
    char* ws = (char*)d_ws;
    size_t off = 0;
    auto alloc = [&](size_t bytes) {
        char* p = ws + off;
        off += (bytes + 255) & ~(size_t)255;
        return (void*)p;
    };
    bf16*  xzb   = (bf16*) alloc((size_t)NROWS * 4096 * 2);   // 64 MB; x_inner half reused as U
    bf16*  xc    = (bf16*) alloc((size_t)NROWS * 2048 * 2);   // 32 MB
    bf16*  dtb   = (bf16*) alloc((size_t)NROWS * 2048 * 2);   // 32 MB; first 8 MB aliased by WinT
    float* bdt   = (float*)alloc((size_t)NROWS * 128 * 4);    //  4 MB
    bf16*  WcombT= (bf16*) alloc((size_t)2176 * 2048 * 2);    //  8.5 MB (W_dt^T ++ W_x^T pad128)
    bf16*  WoutT = (bf16*) alloc((size_t)1024 * 2048 * 2);    //  4 MB
    char*  scr   = (char*) alloc((size_t)16 << 20);           // 16 MB shared scratch
    // aliases (lifetimes verified):
    bf16*  WinT = (bf16*)dtb;          // used only by GEMM1; dt written later by merged GEMM
    bf16*  x_bf = (bf16*)scr;          // used only by GEMM1 (16 MB)
    float* Pb   = (float*)scr;         // written in pass1 (8 MB), after GEMM1
    float* Sb   = (float*)(scr + ((size_t)8 << 20));  // 8 MB
    float* Hb   = Pb;                  // pass2 writes Hinit in-place over P
    bf16*  U    = xzb;                 // pass3 writes U over dead x_inner half

    // ---- fused weight prep + x cast (one dispatch) -------------------------
    prep<<<18688, 256, 0, stream>>>(x, W_in, W_dt, W_x, W_out,
                                    x_bf, WinT, WcombT, WoutT);

    // xz = x @ W_in  (bf16 out, row stride 4096)
    gemm_bt<2><<<dim3(4096/128, NROWS/128), 256, 0, stream>>>(x_bf, 1024, WinT, 1024, nullptr, xzb, 4096, nullptr, 1024);
    // xc = silu(causal_conv(x_inner) + b)
    conv_silu<<<(NROWS * 256) / 256, 256, 0, stream>>>(xzb, conv_w, conv_b, xc);
    // merged: dt = softplus(xc @ W_dt + b_dt) [cols 0..2047, bf16]
    //         bdt = xc @ W_x                  [cols 2048..2175 -> fp32, ld 128]
    gemm_bt<3><<<dim3(2176/128, NROWS/128), 256, 0, stream>>>(xc, 2048, WcombT, 2048, bdt, dtb, 2048, b_dt, 2048);
    // chunked selective scan
    scan_pass1<<<dim3(DINNER/256, NCHUNK, NBATCH), 256, 0, stream>>>(xc, dtb, bdt, A_log, Pb, Sb);
    scan_pass2<<<(NBATCH * DINNER * 16) / 256, 256, 0, stream>>>(Pb, Sb, Hb);
    scan_pass3<<<dim3(DINNER/256, NCHUNK, NBATCH), 256, 0, stream>>>(xc, dtb, bdt, A_log, Hb, xzb, Dp, U);
    // out = U @ W_out  (U row stride 4096)
    gemm_bt<0><<<dim3(1024/128, NROWS/128), 256, 0, stream>>>(U, 4096, WoutT, 2048, out, nullptr, 1024, nullptr, 2048);
}

// Round 8
// 683.690 us; speedup vs baseline: 1.1262x; 1.0079x over previous
//
#include <hip/hip_runtime.h>
#include <hip/hip_bf16.h>

typedef __hip_bfloat16 bf16;
typedef __attribute__((ext_vector_type(8))) short bf16x8;
typedef __attribute__((ext_vector_type(4))) float f32x4;

#define SEQ     2048
#define DMODEL  1024
#define DINNER  2048
#define NBATCH  4
#define NROWS   (NBATCH * SEQ)   // 8192
#define DSTATE  16
#define NCHUNK  16
#define CHUNK   128              // SEQ / NCHUNK
#define LDSP    40               // padded LDS row stride (elems): bank-base
                                 // row*20 mod 32, period 8 -> b128 ops 2-way max

__device__ __forceinline__ float b2f(short s) {
    union { unsigned u; float f; } c;
    c.u = ((unsigned)(unsigned short)s) << 16;
    return c.f;
}

// ---------------------------------------------------------------------------
// Fused weight-prep kernel: one dispatch does all 4 transposes + the x cast.
//   [0,     8192): cast x (fp32->bf16), 4 elems/thread
//   [8192, 12288): W_in  (1024x4096) -> WinT  (4096x1024)
//   [12288,16384): W_dt  (2048x2048) -> WcombT rows 0..2047
//   [16384,16640): W_x   (2048x32)   -> WcombT rows 2048..2175 (pad 128)
//   [16640,18688): W_out (2048x1024) -> WoutT (1024x2048)
// ---------------------------------------------------------------------------
__device__ __forceinline__ void transpose_tile(
    const float* __restrict__ W, bf16* __restrict__ WT,
    int K, int N, int Npad, int bx, int by)
{
    __shared__ float tile[32][33];
    const int tx = threadIdx.x & 31, ty = threadIdx.x >> 5;   // 32 x 8
    const int x = bx * 32 + tx;           // N index
#pragma unroll
    for (int i = 0; i < 32; i += 8) {
        int y = by * 32 + ty + i;         // K index
        tile[ty + i][tx] = (x < N && y < K) ? W[(size_t)y * N + x] : 0.f;
    }
    __syncthreads();
    const int k = by * 32 + tx;
#pragma unroll
    for (int i = 0; i < 32; i += 8) {
        int n = bx * 32 + ty + i;
        if (n < Npad && k < K)
            WT[(size_t)n * K + k] = __float2bfloat16(tile[tx][ty + i]);
    }
}

__global__ __launch_bounds__(256)
void prep(const float* __restrict__ x,     const float* __restrict__ W_in,
          const float* __restrict__ W_dt,  const float* __restrict__ W_x,
          const float* __restrict__ W_out, bf16* __restrict__ x_bf,
          bf16* __restrict__ WinT, bf16* __restrict__ WcombT,
          bf16* __restrict__ WoutT)
{
    const int bid = blockIdx.x;
    if (bid < 8192) {
        int i = bid * 256 + threadIdx.x;          // x cast: 8.4M elems / 4
        float4 v = *(const float4*)(x + (size_t)i * 4);
        __align__(8) bf16 o[4] = { __float2bfloat16(v.x), __float2bfloat16(v.y),
                                   __float2bfloat16(v.z), __float2bfloat16(v.w) };
        *(uint2*)(x_bf + (size_t)i * 4) = *(uint2*)o;
    } else if (bid < 12288) {
        int t = bid - 8192;                       // W_in: 128 x 32 tiles
        transpose_tile(W_in, WinT, 1024, 4096, 4096, t & 127, t >> 7);
    } else if (bid < 16384) {
        int t = bid - 12288;                      // W_dt: 64 x 64 tiles
        transpose_tile(W_dt, WcombT, 2048, 2048, 2048, t & 63, t >> 6);
    } else if (bid < 16640) {
        int t = bid - 16384;                      // W_x: 4 x 64 tiles
        transpose_tile(W_x, WcombT + (size_t)2048 * 2048, 2048, 32, 128,
                       t & 3, t >> 2);
    } else {
        int t = bid - 16640;                      // W_out: 32 x 64 tiles
        transpose_tile(W_out, WoutT, 2048, 1024, 1024, t & 31, t >> 5);
    }
}

// ---------------------------------------------------------------------------
// GEMM: C[M,N] = A[M,K] @ B^T[N,K]   (bf16 in, fp32 accum).
// A row stride lda, BT row stride ldb, C row stride ldc.
// MODE 0: store fp32.  MODE 2: store bf16.
// MODE 3: merged dt/bdt epilogue — col <  DINNER: bf16 softplus(acc+bias[col])
//                                  col >= DINNER: fp32 to Cf[row*128+col-DINNER]
// 128x128 tile, BK=32, 256 threads (4 waves, 64x64 each, 4x4 MFMA tiles).
// R2 staging structure (measured best): register prefetch of tile k+1 issued
// after the publishing barrier, ds_write into single-buffered LDS.
// R7 post-mortem arithmetic: ~12 waves/CU x 144 LDS-cyc/iter vs 78 MFMA-cyc
// -> LDS pipe saturated ~1.9:1; bank conflicts (~20% of LDS pipe) ARE on the
// critical path. Fix here: LDS row stride padded 32->40 elems (bank-base
// row*20 mod 32, period 8) -> all b128 reads/writes max 2-way (free, m136).
// Group-of-8 m-panel swizzle for L2 (R5 vs R7: FETCH 240->97 MB).
// ---------------------------------------------------------------------------
template <int MODE>
__global__ __launch_bounds__(256, 2)
void gemm_bt(const bf16* __restrict__ A, int lda, const bf16* __restrict__ BT,
             int ldb, float* __restrict__ Cf, bf16* __restrict__ Cb, int ldc,
             const float* __restrict__ bias, int K)
{
    __shared__ __align__(16) bf16 As[128 * LDSP];
    __shared__ __align__(16) bf16 Bs[128 * LDSP];
    const int tid  = threadIdx.x;
    const int lane = tid & 63;
    const int wave = tid >> 6;

    // ---- group-of-8 m-panel swizzle (L2/L3 reuse) ----
    const int gx = gridDim.x, gy = gridDim.y;
    int lin = blockIdx.y * gx + blockIdx.x;
    const int per = 8 * gx;
    int g   = lin / per;
    int rem = lin - g * per;
    int rows = min(8, gy - g * 8);
    const int by = g * 8 + rem % rows;
    const int bx = rem / rows;

    const int m0 = by * 128;
    const int n0 = bx * 128;
    const int wm = (wave & 1) * 64;
    const int wn = (wave >> 1) * 64;

    f32x4 acc[4][4];
#pragma unroll
    for (int i = 0; i < 4; ++i)
#pragma unroll
        for (int j = 0; j < 4; ++j) acc[i][j] = (f32x4){0.f, 0.f, 0.f, 0.f};

    // staging: 512 16B-chunks per tile, 2 per thread; chunk c -> row c>>2,
    // slot c&3; LDS addr row*LDSP + slot*8
    const int c0 = tid, c1 = tid + 256;
    const int ar0 = c0 >> 2, ac0 = (c0 & 3) * 8;
    const int ar1 = c1 >> 2, ac1 = (c1 & 3) * 8;
    const int l0 = ar0 * LDSP + ac0;
    const int l1 = ar1 * LDSP + ac1;
    const bf16* pa0 = A  + (size_t)(m0 + ar0) * lda + ac0;
    const bf16* pa1 = A  + (size_t)(m0 + ar1) * lda + ac1;
    const bf16* pb0 = BT + (size_t)(n0 + ar0) * ldb + ac0;
    const bf16* pb1 = BT + (size_t)(n0 + ar1) * ldb + ac1;

    bf16x8 va0 = *(const bf16x8*)pa0;
    bf16x8 va1 = *(const bf16x8*)pa1;
    bf16x8 vb0 = *(const bf16x8*)pb0;
    bf16x8 vb1 = *(const bf16x8*)pb1;

    const int arow = lane & 15;
    const int akq  = (lane >> 4) * 8;
    const int KT = K >> 5;

    for (int kt = 0; kt < KT; ++kt) {
        __syncthreads();   // previous iteration's LDS reads done
        *(bf16x8*)(As + l0) = va0;
        *(bf16x8*)(As + l1) = va1;
        *(bf16x8*)(Bs + l0) = vb0;
        *(bf16x8*)(Bs + l1) = vb1;
        __syncthreads();
        if (kt + 1 < KT) {          // register prefetch of next tile
            int k0 = (kt + 1) * 32;
            va0 = *(const bf16x8*)(pa0 + k0);
            va1 = *(const bf16x8*)(pa1 + k0);
            vb0 = *(const bf16x8*)(pb0 + k0);
            vb1 = *(const bf16x8*)(pb1 + k0);
        }
        bf16x8 af[4], bfr[4];
#pragma unroll
        for (int i = 0; i < 4; ++i)
            af[i] = *(const bf16x8*)(As + (wm + i * 16 + arow) * LDSP + akq);
#pragma unroll
        for (int j = 0; j < 4; ++j)
            bfr[j] = *(const bf16x8*)(Bs + (wn + j * 16 + arow) * LDSP + akq);
#pragma unroll
        for (int i = 0; i < 4; ++i)
#pragma unroll
            for (int j = 0; j < 4; ++j)
                acc[i][j] = __builtin_amdgcn_mfma_f32_16x16x32_bf16(
                    af[i], bfr[j], acc[i][j], 0, 0, 0);
    }

    // epilogue: C/D layout col = lane&15, row = (lane>>4)*4 + reg
    const int rbase = (lane >> 4) * 4;
    const int cbase = lane & 15;
#pragma unroll
    for (int i = 0; i < 4; ++i) {
        int row = m0 + wm + i * 16 + rbase;
#pragma unroll
        for (int j = 0; j < 4; ++j) {
            int col = n0 + wn + j * 16 + cbase;
#pragma unroll
            for (int r = 0; r < 4; ++r) {
                float v = acc[i][j][r];
                if (MODE == 0) {
                    Cf[(size_t)(row + r) * ldc + col] = v;
                } else if (MODE == 2) {
                    Cb[(size_t)(row + r) * ldc + col] = __float2bfloat16(v);
                } else {   // MODE 3 (uniform per block: n0==2048 -> bdt path)
                    if (col < DINNER) {
                        float v2 = v + bias[col];
                        float sp = (v2 > 20.f) ? v2 : log1pf(__expf(v2));
                        Cb[(size_t)(row + r) * ldc + col] = __float2bfloat16(sp);
                    } else {
                        Cf[(size_t)(row + r) * 128 + (col - DINNER)] = v;
                    }
                }
            }
        }
    }
}

// ---------------------------------------------------------------------------
// Causal depthwise conv (d_conv=4) + bias + SiLU. Reads bf16 x_inner =
// xz[:, :2048] (row stride 4096). One thread per (row, 8 channels).
// ---------------------------------------------------------------------------
__global__ __launch_bounds__(256)
void conv_silu(const bf16* __restrict__ xz, const float* __restrict__ conv_w,
               const float* __restrict__ conv_b, bf16* __restrict__ xc)
{
    int gid = blockIdx.x * 256 + threadIdx.x;   // NROWS * 256
    int d8  = gid & 255;
    int row = gid >> 8;
    int l   = row & (SEQ - 1);
    int d   = d8 * 8;
    const bf16* base = xz + (size_t)row * 4096 + d;
    float acc[8];
    float4 b0 = *(const float4*)(conv_b + d);
    float4 b1 = *(const float4*)(conv_b + d + 4);
    acc[0] = b0.x; acc[1] = b0.y; acc[2] = b0.z; acc[3] = b0.w;
    acc[4] = b1.x; acc[5] = b1.y; acc[6] = b1.z; acc[7] = b1.w;
    float w[8][4];
#pragma unroll
    for (int j = 0; j < 8; ++j) {
        float4 wv = *(const float4*)(conv_w + (size_t)(d + j) * 4);
        w[j][0] = wv.x; w[j][1] = wv.y; w[j][2] = wv.z; w[j][3] = wv.w;
    }
#pragma unroll
    for (int k = 0; k < 4; ++k) {
        if (l + k - 3 >= 0) {   // wave-uniform branch (row is block-uniform)
            bf16x8 v = *(const bf16x8*)(base + (ptrdiff_t)(k - 3) * 4096);
#pragma unroll
            for (int j = 0; j < 8; ++j)
                acc[j] = fmaf(b2f(v[j]), w[j][k], acc[j]);
        }
    }
    __align__(16) bf16 o[8];
#pragma unroll
    for (int j = 0; j < 8; ++j) {
        float s = acc[j] / (1.f + __expf(-acc[j]));
        o[j] = __float2bfloat16(s);
    }
    *(bf16x8*)(xc + (size_t)row * DINNER + d) = *(bf16x8*)o;
}

// ---------------------------------------------------------------------------
// Chunked selective scan, pass 1: per (b, chunk, d): P = prod(a_t), S = local h
// layout P/S[c][b][d][n].  dt/xc loads software-pipelined (prefetch t+1).
// ---------------------------------------------------------------------------
__global__ __launch_bounds__(256)
void scan_pass1(const bf16* __restrict__ xc, const bf16* __restrict__ dt,
                const float* __restrict__ bdt, const float* __restrict__ A_log,
                float* __restrict__ P, float* __restrict__ S)
{
    const int d  = blockIdx.x * 256 + threadIdx.x;
    const int c  = blockIdx.y;
    const int b  = blockIdx.z;
    const int t0 = c * CHUNK;
    __shared__ float bls[CHUNK][DSTATE];
    for (int i = threadIdx.x; i < CHUNK * DSTATE; i += 256) {
        int tl = i >> 4, col = i & 15;
        bls[tl][col] = bdt[(size_t)(b * SEQ + t0 + tl) * 128 + col];
    }
    __syncthreads();
    float acoef[16], h[16], p[16];
#pragma unroll
    for (int n = 0; n < 16; ++n) {
        acoef[n] = -__expf(A_log[(size_t)d * 16 + n]) * 1.44269504f;
        h[n] = 0.f; p[n] = 1.f;
    }
    size_t idx = (size_t)(b * SEQ + t0) * DINNER + d;
    bf16 dcur = dt[idx], xcur = xc[idx];
    for (int tl = 0; tl < CHUNK; ++tl) {
        bf16 dnext = dcur, xnext = xcur;
        if (tl + 1 < CHUNK) {                 // prefetch next timestep
            dnext = dt[idx + DINNER];
            xnext = xc[idx + DINNER];
        }
        float dtv = __bfloat162float(dcur);
        float xv  = __bfloat162float(xcur);
        float u = dtv * xv;
#pragma unroll
        for (int n = 0; n < 16; ++n) {
            float a = exp2f(dtv * acoef[n]);
            p[n] *= a;
            h[n] = fmaf(a, h[n], u * bls[tl][n]);
        }
        dcur = dnext; xcur = xnext; idx += DINNER;
    }
    size_t o = ((size_t)(c * NBATCH + b) * DINNER + d) * 16;
#pragma unroll
    for (int n = 0; n < 16; n += 4) {
        *(float4*)(P + o + n) = make_float4(p[n], p[n+1], p[n+2], p[n+3]);
        *(float4*)(S + o + n) = make_float4(h[n], h[n+1], h[n+2], h[n+3]);
    }
}

// ---------------------------------------------------------------------------
// Pass 2: sequential combine over chunks. One thread per (b,d,n).
// Hinit may alias P (each element read before overwrite, one owner thread).
// ---------------------------------------------------------------------------
__global__ __launch_bounds__(256)
void scan_pass2(const float* __restrict__ P, const float* __restrict__ S,
                float* __restrict__ Hinit)
{
    size_t idx = (size_t)blockIdx.x * 256 + threadIdx.x;
    const size_t stride = (size_t)NBATCH * DINNER * 16;
    float h = 0.f;
    for (int c = 0; c < NCHUNK; ++c) {
        size_t o = (size_t)c * stride + idx;
        float p = P[o];
        float s = S[o];
        Hinit[o] = h;
        h = fmaf(p, h, s);
    }
}

// ---------------------------------------------------------------------------
// Pass 3: replay chunk from true h_init; fuse y = scan + xc*D, * silu(z),
// cast bf16 into U (row stride 4096; reads z from cols 2048.. of same buffer).
// dt/xc/z loads software-pipelined (prefetch t+1).
// ---------------------------------------------------------------------------
__global__ __launch_bounds__(256)
void scan_pass3(const bf16* __restrict__ xc, const bf16* __restrict__ dt,
                const float* __restrict__ bdt, const float* __restrict__ A_log,
                const float* __restrict__ Hinit, const bf16* __restrict__ xzb,
                const float* __restrict__ Dp, bf16* __restrict__ U)
{
    const int d  = blockIdx.x * 256 + threadIdx.x;
    const int c  = blockIdx.y;
    const int b  = blockIdx.z;
    const int t0 = c * CHUNK;
    __shared__ float bls[CHUNK][DSTATE];
    __shared__ float cls[CHUNK][DSTATE];
    for (int i = threadIdx.x; i < CHUNK * 32; i += 256) {
        int tl = i >> 5, col = i & 31;
        float v = bdt[(size_t)(b * SEQ + t0 + tl) * 128 + col];
        if (col < 16) bls[tl][col] = v; else cls[tl][col - 16] = v;
    }
    __syncthreads();
    float acoef[16], h[16];
#pragma unroll
    for (int n = 0; n < 16; ++n)
        acoef[n] = -__expf(A_log[(size_t)d * 16 + n]) * 1.44269504f;
    size_t ho = ((size_t)(c * NBATCH + b) * DINNER + d) * 16;
#pragma unroll
    for (int n = 0; n < 16; n += 4) {
        float4 hv = *(const float4*)(Hinit + ho + n);
        h[n] = hv.x; h[n+1] = hv.y; h[n+2] = hv.z; h[n+3] = hv.w;
    }
    const float Dv = Dp[d];
    size_t idx  = (size_t)(b * SEQ + t0) * DINNER + d;
    size_t widx = (size_t)(b * SEQ + t0) * 4096 + d;   // U col d / z col 2048+d
    bf16 dcur = dt[idx], xcur = xc[idx], zcur = xzb[widx + DINNER];
    for (int tl = 0; tl < CHUNK; ++tl) {
        bf16 dnext = dcur, xnext = xcur, znext = zcur;
        if (tl + 1 < CHUNK) {                 // prefetch next timestep
            dnext = dt[idx + DINNER];
            xnext = xc[idx + DINNER];
            znext = xzb[widx + 4096 + DINNER];
        }
        float dtv = __bfloat162float(dcur);
        float xv  = __bfloat162float(xcur);
        float u = dtv * xv;
        float y = 0.f;
#pragma unroll
        for (int n = 0; n < 16; ++n) {
            float a = exp2f(dtv * acoef[n]);
            h[n] = fmaf(a, h[n], u * bls[tl][n]);
            y = fmaf(h[n], cls[tl][n], y);
        }
        float zv = __bfloat162float(zcur);
        float sz = zv / (1.f + __expf(-zv));
        float val = (y + xv * Dv) * sz;
        U[widx] = __float2bfloat16(val);
        dcur = dnext; xcur = xnext; zcur = znext;
        idx += DINNER; widx += 4096;
    }
}

// ---------------------------------------------------------------------------
extern "C" void kernel_launch(void* const* d_in, const int* in_sizes, int n_in,
                              void* d_out, int out_size, void* d_ws, size_t ws_size,
                              hipStream_t stream)
{
    const float* x      = (const float*)d_in[0];
    const float* W_in   = (const float*)d_in[1];
    const float* conv_w = (const float*)d_in[2];
    const float* conv_b = (const float*)d_in[3];
    const float* W_x    = (const float*)d_in[4];
    const float* W_dt   = (const float*)d_in[5];
    const float* b_dt   = (const float*)d_in[6];
    const float* W_out  = (const float*)d_in[7];
    const float* A_log  = (const float*)d_in[8];
    const float* Dp     = (const float*)d_in[9];
    float* out = (float*)d_out;

    // ---- workspace layout (~161 MB total, lifetime-checked aliasing) -------
    char* ws = (char*)d_ws;
    size_t off = 0;
    auto alloc = [&](size_t bytes) {
        char* p = ws + off;
        off += (bytes + 255) & ~(size_t)255;
        return (void*)p;
    };
    bf16*  xzb   = (bf16*) alloc((size_t)NROWS * 4096 * 2);   // 64 MB; x_inner half reused as U
    bf16*  xc    = (bf16*) alloc((size_t)NROWS * 2048 * 2);   // 32 MB
    bf16*  dtb   = (bf16*) alloc((size_t)NROWS * 2048 * 2);   // 32 MB; first 8 MB aliased by WinT
    float* bdt   = (float*)alloc((size_t)NROWS * 128 * 4);    //  4 MB
    bf16*  WcombT= (bf16*) alloc((size_t)2176 * 2048 * 2);    //  8.5 MB (W_dt^T ++ W_x^T pad128)
    bf16*  WoutT = (bf16*) alloc((size_t)1024 * 2048 * 2);    //  4 MB
    char*  scr   = (char*) alloc((size_t)16 << 20);           // 16 MB shared scratch
    // aliases (lifetimes verified):
    bf16*  WinT = (bf16*)dtb;          // used only by GEMM1; dt written later by merged GEMM
    bf16*  x_bf = (bf16*)scr;          // used only by GEMM1 (16 MB)
    float* Pb   = (float*)scr;         // written in pass1 (8 MB), after GEMM1
    float* Sb   = (float*)(scr + ((size_t)8 << 20));  // 8 MB
    float* Hb   = Pb;                  // pass2 writes Hinit in-place over P
    bf16*  U    = xzb;                 // pass3 writes U over dead x_inner half

    // ---- fused weight prep + x cast (one dispatch) -------------------------
    prep<<<18688, 256, 0, stream>>>(x, W_in, W_dt, W_x, W_out,
                                    x_bf, WinT, WcombT, WoutT);

    // xz = x @ W_in  (bf16 out, row stride 4096)
    gemm_bt<2><<<dim3(4096/128, NROWS/128), 256, 0, stream>>>(x_bf, 1024, WinT, 1024, nullptr, xzb, 4096, nullptr, 1024);
    // xc = silu(causal_conv(x_inner) + b)
    conv_silu<<<(NROWS * 256) / 256, 256, 0, stream>>>(xzb, conv_w, conv_b, xc);
    // merged: dt = softplus(xc @ W_dt + b_dt) [cols 0..2047, bf16]
    //         bdt = xc @ W_x                  [cols 2048..2175 -> fp32, ld 128]
    gemm_bt<3><<<dim3(2176/128, NROWS/128), 256, 0, stream>>>(xc, 2048, WcombT, 2048, bdt, dtb, 2048, b_dt, 2048);
    // chunked selective scan
    scan_pass1<<<dim3(DINNER/256, NCHUNK, NBATCH), 256, 0, stream>>>(xc, dtb, bdt, A_log, Pb, Sb);
    scan_pass2<<<(NBATCH * DINNER * 16) / 256, 256, 0, stream>>>(Pb, Sb, Hb);
    scan_pass3<<<dim3(DINNER/256, NCHUNK, NBATCH), 256, 0, stream>>>(xc, dtb, bdt, A_log, Hb, xzb, Dp, U);
    // out = U @ W_out  (U row stride 4096)
    gemm_bt<0><<<dim3(1024/128, NROWS/128), 256, 0, stream>>>(U, 4096, WoutT, 2048, out, nullptr, 1024, nullptr, 2048);
}